// Round 8
// baseline (4249.292 us; speedup 1.0000x reference)
//
#include <hip/hip_runtime.h>
#include <hip/hip_bf16.h>

typedef _Float16 half8 __attribute__((ext_vector_type(8)));
typedef _Float16 half4 __attribute__((ext_vector_type(4)));
typedef float floatx4 __attribute__((ext_vector_type(4)));

__device__ __forceinline__ float bfu2f(unsigned short u) {
  return __uint_as_float(((unsigned)u) << 16);
}

__device__ __forceinline__ void gld16(const void* g, void* l) {
  __builtin_amdgcn_global_load_lds((const __attribute__((address_space(1))) void*)g,
                                   (__attribute__((address_space(3))) void*)l, 16, 0, 0);
}

__device__ __forceinline__ float fast_sig(float v) {
  return __builtin_amdgcn_rcpf(1.f + __expf(-v));
}

// XCD-aware decode: all NC col-blocks of a row-block share lin%8 -> same XCD.
template <int NC>
__device__ __forceinline__ void xcd_decode(int lin, int NR, int& r, int& c) {
  if (NR & 7) {  // fallback
    c = lin % NC;
    r = lin / NC;
  } else {
    int rl = lin & 7;
    int t = lin >> 3;
    c = t % NC;
    r = (t / NC) * 8 + rl;
  }
}

// ---------- probe: detect fp32 vs bf16 inputs (writes flag: 1 = fp32) ----------
__global__ void probe_kernel(const unsigned short* __restrict__ w0, int* __restrict__ flag) {
  __shared__ int s;
  if (threadIdx.x == 0) s = 0;
  __syncthreads();
  int big = 0;
  for (int i = threadIdx.x; i < 2048; i += 256) {
    unsigned e = (w0[i] >> 7) & 0xFFu;
    if (e >= 134u) big = 1;  // |val| >= 128 impossible for bf16 N(0,0.7) weights
  }
  if (big) atomicOr(&s, 1);
  __syncthreads();
  if (threadIdx.x == 0) *flag = s;
}

// ---------- generic convert to fp16 (zero-pads nIn..nOut) ----------
__global__ void cvt_kernel(const void* __restrict__ in, _Float16* __restrict__ out, int nOut,
                           int nIn, const int* __restrict__ flag) {
  int i = blockIdx.x * 256 + threadIdx.x;
  if (i >= nOut) return;
  float v = 0.f;
  if (i < nIn) v = (*flag) ? ((const float*)in)[i] : bfu2f(((const unsigned short*)in)[i]);
  out[i] = (_Float16)v;
}

// ---------- transpose+convert: out[z][n][k] = in[z][k][n] (n<Nin else 0), K=1024 ----------
__global__ void tr_kernel(const void* __restrict__ in, _Float16* __restrict__ out, int Nin,
                          long inStride, long outStride, const int* __restrict__ flag) {
  __shared__ float tile[32][33];
  const int f = *flag;
  int k0 = blockIdx.x * 32, n0 = blockIdx.y * 32;
  long ib = (long)blockIdx.z * inStride;
  long ob = (long)blockIdx.z * outStride;
  int tx = threadIdx.x, ty = threadIdx.y;  // 32 x 8
#pragma unroll
  for (int i = 0; i < 4; i++) {
    int k = k0 + ty + i * 8, n = n0 + tx;
    float v = 0.f;
    if (n < Nin) {
      long idx = ib + (long)k * Nin + n;
      v = f ? ((const float*)in)[idx] : bfu2f(((const unsigned short*)in)[idx]);
    }
    tile[ty + i * 8][tx] = v;
  }
  __syncthreads();
#pragma unroll
  for (int i = 0; i < 4; i++) {
    int n = n0 + ty + i * 8, k = k0 + tx;
    out[ob + (long)n * 1024 + k] = (_Float16)tile[tx][ty + i * 8];
  }
}

// ---------- layer 0: primal + 4 tangent init ----------
__global__ __launch_bounds__(256)
void layer0_kernel(const _Float16* __restrict__ x16, const _Float16* __restrict__ W0c,
                   const _Float16* __restrict__ b0c, _Float16* __restrict__ H,
                   int chunkBase, int S1) {
  const int lb = blockIdx.x;
  const int t = threadIdx.x;
  const long gb = (long)chunkBase + lb;
  float z0 = (float)x16[gb * 4 + 0];
  float z1 = (float)x16[gb * 4 + 1];
  float z2 = (float)x16[gb * 4 + 2];
  float z3 = (float)x16[gb * 4 + 3];
  const int j0 = t * 4;
  float w[4][4];
#pragma unroll
  for (int i = 0; i < 4; i++) {
    half4 wv = *(const half4*)&W0c[i * 1024 + j0];
#pragma unroll
    for (int jj = 0; jj < 4; jj++) w[i][jj] = (float)wv[jj];
  }
  half4 o[5];
#pragma unroll
  for (int jj = 0; jj < 4; jj++) {
    float pre = z0 * w[0][jj] + z1 * w[1][jj] + z2 * w[2][jj] + z3 * w[3][jj] +
                (float)b0c[j0 + jj];
    float s = fast_sig(pre);
    o[0][jj] = (_Float16)(pre * s);
    float ds = s * (1.f + pre * (1.f - s));
    o[1][jj] = (_Float16)(ds * w[0][jj]);
    o[2][jj] = (_Float16)(ds * w[1][jj]);
    o[3][jj] = (_Float16)(ds * w[2][jj]);
    o[4][jj] = (_Float16)(ds * w[3][jj]);
  }
  long rowbase = (long)lb * 1024 + j0;
#pragma unroll
  for (int s = 0; s < 5; s++) *(half4*)&H[(long)s * S1 + rowbase] = o[s];
}

// ---------- hidden primal GEMM, 128x128 drain-style (fallback for Bc < 256) ----------
__global__ __launch_bounds__(256, 3)
void gemm_h1(const _Float16* __restrict__ A, const _Float16* __restrict__ Bt,
             const _Float16* __restrict__ bias, _Float16* __restrict__ C,
             _Float16* __restrict__ DS, int NR) {
  constexpr int K = 1024;
  __shared__ _Float16 SM[8192];  // As(4096) + Bs(4096); Ep(8192) overlaps after K-loop
  _Float16* As = SM;
  _Float16* Bs = SM + 4096;
  _Float16* Ep = SM;
  const int tid = threadIdx.x;
  const int wave = tid >> 6;
  const int lane = tid & 63;
  int rb, cb;
  xcd_decode<8>(blockIdx.x, NR, rb, cb);
  const int n0 = cb * 128;
  const long m0 = (long)rb * 128;

  const int srow0 = (wave * 2 + 0) * 16 + (lane >> 2);
  const int srow1 = (wave * 2 + 1) * 16 + (lane >> 2);
  const int scol = (lane & 3) * 8;
  const _Float16* gA0 = A + (m0 + srow0) * K + scol;
  const _Float16* gA1 = A + (m0 + srow1) * K + scol;
  const _Float16* gB0 = Bt + (long)(n0 + srow0) * K + scol;
  const _Float16* gB1 = Bt + (long)(n0 + srow1) * K + scol;
  _Float16* lA0 = As + (wave * 2 + 0) * 512;
  _Float16* lA1 = As + (wave * 2 + 1) * 512;
  _Float16* lB0 = Bs + (wave * 2 + 0) * 512;
  _Float16* lB1 = Bs + (wave * 2 + 1) * 512;

  const int wm = (wave & 1) * 64;
  const int wn = (wave >> 1) * 64;
  const int fr = lane & 15;
  const int fc = (lane >> 4) * 8;
  const int c0f = lane & 15;
  const int rqk = lane >> 4;
  const int myRound = wave & 1;

  float bv[4];
#pragma unroll
  for (int ni = 0; ni < 4; ni++) bv[ni] = (float)bias[n0 + wn + ni * 16 + c0f];

  const int erow = tid >> 4;
  const int ecol = (tid & 15) * 8;
  const int ecolp = ecol ^ (wave << 4);

  floatx4 acc[4][4];
#pragma unroll
  for (int i = 0; i < 4; i++)
#pragma unroll
    for (int j = 0; j < 4; j++) acc[i][j] = (floatx4)(0.f);

  for (int kk = 0; kk < K; kk += 32) {
    __syncthreads();
    gld16(gA0 + kk, lA0);
    gld16(gA1 + kk, lA1);
    gld16(gB0 + kk, lB0);
    gld16(gB1 + kk, lB1);
    __syncthreads();
    half8 af[4], bf[4];
#pragma unroll
    for (int i = 0; i < 4; i++) af[i] = *(const half8*)&As[(wm + i * 16 + fr) * 32 + fc];
#pragma unroll
    for (int i = 0; i < 4; i++) bf[i] = *(const half8*)&Bs[(wn + i * 16 + fr) * 32 + fc];
#pragma unroll
    for (int mi = 0; mi < 4; mi++)
#pragma unroll
      for (int ni = 0; ni < 4; ni++)
        acc[mi][ni] = __builtin_amdgcn_mfma_f32_16x16x32_f16(af[mi], bf[ni], acc[mi][ni], 0, 0, 0);
  }

#pragma unroll
  for (int r = 0; r < 2; r++) {
    __syncthreads();
    if (myRound == r) {
#pragma unroll
      for (int mi = 0; mi < 4; mi++)
#pragma unroll
        for (int ni = 0; ni < 4; ni++) {
          int colp = (wn + ni * 16 + c0f) ^ (rqk << 4);
#pragma unroll
          for (int rr = 0; rr < 4; rr++) {
            int row_local = mi * 16 + rqk * 4 + rr;
            Ep[row_local * 128 + colp] = (_Float16)(acc[mi][ni][rr] + bv[ni]);
          }
        }
    }
    __syncthreads();
#pragma unroll
    for (int p = 0; p < 4; p++) {
      int row_local = p * 16 + erow;
      half8 vv = *(const half8*)&Ep[row_local * 128 + ecolp];
      long row = m0 + r * 64 + row_local;
      half8 hv, dv;
#pragma unroll
      for (int e = 0; e < 8; e++) {
        float xv = (float)vv[e];
        float sg = fast_sig(xv);
        hv[e] = (_Float16)(xv * sg);
        dv[e] = (_Float16)(sg * (1.f + xv * (1.f - sg)));
      }
      *(half8*)&C[row * (long)K + n0 + ecol] = hv;
      *(half8*)&DS[row * (long)K + n0 + ecol] = dv;
    }
  }
}

// ---------- hidden primal GEMM, 256x256 tile (r6-proven K-loop + silu epilogue) ----------
// v = A*W^T + b; C = silu(v); DS = silu'(v). K-loop copied verbatim from the
// r6-verified gemm_h2 (3-ring, vmcnt(4), one barrier/step, swizzle pair).
__global__ __launch_bounds__(512, 2)
void gemm_h1_256(const _Float16* __restrict__ A, const _Float16* __restrict__ Bt,
                 const _Float16* __restrict__ bias, _Float16* __restrict__ C,
                 _Float16* __restrict__ DS, int NR) {
  constexpr int K = 1024;
  __shared__ _Float16 SM[49152];
  const int tid = threadIdx.x;
  const int wave = tid >> 6;
  const int lane = tid & 63;
  int rb, cb;
  xcd_decode<4>(blockIdx.x, NR, rb, cb);
  const long m0 = (long)rb * 256;
  const int n0 = cb * 256;

  const int srow = wave * 32 + (lane >> 2);
  const int scol = ((lane & 3) ^ ((lane >> 3) & 3)) * 8;
  const _Float16* gA0 = A + (m0 + srow) * K + scol;
  const _Float16* gA1 = gA0 + 16 * K;
  const _Float16* gB0 = Bt + (long)(n0 + srow) * K + scol;
  const _Float16* gB1 = gB0 + 16 * K;
  const int loff0 = wave * 1024;
  const int loff1 = loff0 + 512;

  const int wr = wave >> 2;
  const int wc = wave & 3;
  const int fr = lane & 15;
  const int fc = ((lane >> 4) ^ ((lane >> 1) & 3)) * 8;
  const int rqk = lane >> 4;
  const int c0f = lane & 15;

  float bv[4];
#pragma unroll
  for (int ni = 0; ni < 4; ni++) bv[ni] = (float)bias[n0 + wc * 64 + ni * 16 + c0f];

  floatx4 acc[8][4];
#pragma unroll
  for (int i = 0; i < 8; i++)
#pragma unroll
    for (int j = 0; j < 4; j++) acc[i][j] = (floatx4)(0.f);

  {
    _Float16* b0p = SM;
    gld16(gA0 + 0, b0p + loff0);
    gld16(gA1 + 0, b0p + loff1);
    gld16(gB0 + 0, b0p + 8192 + loff0);
    gld16(gB1 + 0, b0p + 8192 + loff1);
    _Float16* b1p = SM + 16384;
    gld16(gA0 + 32, b1p + loff0);
    gld16(gA1 + 32, b1p + loff1);
    gld16(gB0 + 32, b1p + 8192 + loff0);
    gld16(gB1 + 32, b1p + 8192 + loff1);
  }

  int bufCur = 0;
  int bufNxt = 2;
  for (int it = 0; it < 32; ++it) {
    if (it < 31) __builtin_amdgcn_s_waitcnt(0x0F74);  // vmcnt(4)
    else         __builtin_amdgcn_s_waitcnt(0x0F70);  // vmcnt(0)
    __builtin_amdgcn_s_barrier();
    const int kk = (it + 2) * 32;
    _Float16* bp = SM + bufNxt * 16384;
    if (it < 30) {
      gld16(gA0 + kk, bp + loff0);
      gld16(gA1 + kk, bp + loff1);
    }
    const _Float16* Asb = SM + bufCur * 16384;
    const _Float16* Bsb = Asb + 8192;
    half8 af[8], bf0, bf1, bf2, bf3;
#pragma unroll
    for (int i = 0; i < 8; i++)
      af[i] = *(const half8*)&Asb[(wr * 128 + i * 16 + fr) * 32 + fc];
    bf0 = *(const half8*)&Bsb[(wc * 64 + 0 * 16 + fr) * 32 + fc];
    bf1 = *(const half8*)&Bsb[(wc * 64 + 1 * 16 + fr) * 32 + fc];
    __builtin_amdgcn_s_setprio(1);
#pragma unroll
    for (int mi = 0; mi < 8; mi++) {
      acc[mi][0] = __builtin_amdgcn_mfma_f32_16x16x32_f16(af[mi], bf0, acc[mi][0], 0, 0, 0);
      acc[mi][1] = __builtin_amdgcn_mfma_f32_16x16x32_f16(af[mi], bf1, acc[mi][1], 0, 0, 0);
    }
    __builtin_amdgcn_s_setprio(0);
    if (it < 30) {
      gld16(gB0 + kk, bp + 8192 + loff0);
      gld16(gB1 + kk, bp + 8192 + loff1);
    }
    bf2 = *(const half8*)&Bsb[(wc * 64 + 2 * 16 + fr) * 32 + fc];
    bf3 = *(const half8*)&Bsb[(wc * 64 + 3 * 16 + fr) * 32 + fc];
    __builtin_amdgcn_s_setprio(1);
#pragma unroll
    for (int mi = 0; mi < 8; mi++) {
      acc[mi][2] = __builtin_amdgcn_mfma_f32_16x16x32_f16(af[mi], bf2, acc[mi][2], 0, 0, 0);
      acc[mi][3] = __builtin_amdgcn_mfma_f32_16x16x32_f16(af[mi], bf3, acc[mi][3], 0, 0, 0);
    }
    __builtin_amdgcn_s_setprio(0);
    bufCur = (bufCur == 2) ? 0 : bufCur + 1;
    bufNxt = (bufNxt == 2) ? 0 : bufNxt + 1;
  }

  // epilogue: 4 rounds of 64 rows x 256 cols via LDS; bias added (fp32) at write,
  // silu/silu' computed at read — numerics match the 128^2 h1 exactly.
  const int erow = tid >> 3;
  const int rqkr = (erow >> 2) & 3;
#pragma unroll
  for (int r = 0; r < 4; ++r) {
    __syncthreads();
    if (wr == (r >> 1)) {
      const int mib = (r & 1) * 4;
#pragma unroll
      for (int mi2 = 0; mi2 < 4; ++mi2) {
#pragma unroll
        for (int ni = 0; ni < 4; ++ni) {
          int colp = (wc * 64 + ni * 16 + c0f) ^ (rqk << 4);
#pragma unroll
          for (int rr = 0; rr < 4; ++rr) {
            int row_local = mi2 * 16 + rqk * 4 + rr;
            SM[row_local * 256 + colp] = (_Float16)(acc[mib + mi2][ni][rr] + bv[ni]);
          }
        }
      }
    }
    __syncthreads();
    long grow = m0 + r * 64 + erow;
#pragma unroll
    for (int q = 0; q < 4; ++q) {
      int col = (tid & 7) * 8 + q * 64;
      int colp = col ^ (rqkr << 4);
      half8 vv = *(const half8*)&SM[erow * 256 + colp];
      half8 hv, dv;
#pragma unroll
      for (int e = 0; e < 8; e++) {
        float xv = (float)vv[e];
        float sg = fast_sig(xv);
        hv[e] = (_Float16)(xv * sg);
        dv[e] = (_Float16)(sg * (1.f + xv * (1.f - sg)));
      }
      *(half8*)&C[grow * (long)K + n0 + col] = hv;
      *(half8*)&DS[grow * (long)K + n0 + col] = dv;
    }
  }
}

// ---------- hidden tangent GEMM, 256x256 tile, 8 waves, single-barrier K-step ----------
// r6-verified form (77.4 us): ring of 3 LDS buffers, prefetch distance 2, counted
// vmcnt(4) + ONE raw barrier per K-step. r7's BK=64 pairing REGRESSED (88 us) —
// the fine 32-K interleave is the value, not fewer barriers. Do not coarsen.
__global__ __launch_bounds__(512, 2)
void gemm_h2(const _Float16* __restrict__ A, const _Float16* __restrict__ Bt,
             _Float16* __restrict__ C, const _Float16* __restrict__ DS, int bcMask, int NR) {
  constexpr int K = 1024;
  __shared__ _Float16 SM[49152];  // 3 x (A 8192 + B 8192) elems = 96 KB; epilogue overlays
  const int tid = threadIdx.x;
  const int wave = tid >> 6;
  const int lane = tid & 63;
  int rb, cb;
  xcd_decode<4>(blockIdx.x, NR, rb, cb);
  const long m0 = (long)rb * 256;
  const int n0 = cb * 256;

  const int srow = wave * 32 + (lane >> 2);
  const int scol = ((lane & 3) ^ ((lane >> 3) & 3)) * 8;  // pre-swizzled source chunk
  const _Float16* gA0 = A + (m0 + srow) * K + scol;
  const _Float16* gA1 = gA0 + 16 * K;
  const _Float16* gB0 = Bt + (long)(n0 + srow) * K + scol;
  const _Float16* gB1 = gB0 + 16 * K;
  const int loff0 = wave * 1024;
  const int loff1 = loff0 + 512;

  const int wr = wave >> 2;
  const int wc = wave & 3;
  const int fr = lane & 15;
  const int fc = ((lane >> 4) ^ ((lane >> 1) & 3)) * 8;  // swizzled read slot
  const int rqk = lane >> 4;
  const int c0f = lane & 15;

  floatx4 acc[8][4];
#pragma unroll
  for (int i = 0; i < 8; i++)
#pragma unroll
    for (int j = 0; j < 4; j++) acc[i][j] = (floatx4)(0.f);

  {
    _Float16* b0p = SM;
    gld16(gA0 + 0, b0p + loff0);
    gld16(gA1 + 0, b0p + loff1);
    gld16(gB0 + 0, b0p + 8192 + loff0);
    gld16(gB1 + 0, b0p + 8192 + loff1);
    _Float16* b1p = SM + 16384;
    gld16(gA0 + 32, b1p + loff0);
    gld16(gA1 + 32, b1p + loff1);
    gld16(gB0 + 32, b1p + 8192 + loff0);
    gld16(gB1 + 32, b1p + 8192 + loff1);
  }

  int bufCur = 0;
  int bufNxt = 2;
  for (int it = 0; it < 32; ++it) {
    if (it < 31) __builtin_amdgcn_s_waitcnt(0x0F74);  // vmcnt(4): step it complete
    else         __builtin_amdgcn_s_waitcnt(0x0F70);  // vmcnt(0)
    __builtin_amdgcn_s_barrier();                     // raw: no forced drain of step it+1
    const int kk = (it + 2) * 32;
    _Float16* bp = SM + bufNxt * 16384;
    if (it < 30) {  // phase-1 staging: A-pair for step it+2
      gld16(gA0 + kk, bp + loff0);
      gld16(gA1 + kk, bp + loff1);
    }
    const _Float16* Asb = SM + bufCur * 16384;
    const _Float16* Bsb = Asb + 8192;
    half8 af[8], bf0, bf1, bf2, bf3;
#pragma unroll
    for (int i = 0; i < 8; i++)
      af[i] = *(const half8*)&Asb[(wr * 128 + i * 16 + fr) * 32 + fc];
    bf0 = *(const half8*)&Bsb[(wc * 64 + 0 * 16 + fr) * 32 + fc];
    bf1 = *(const half8*)&Bsb[(wc * 64 + 1 * 16 + fr) * 32 + fc];
    __builtin_amdgcn_s_setprio(1);
#pragma unroll
    for (int mi = 0; mi < 8; mi++) {
      acc[mi][0] = __builtin_amdgcn_mfma_f32_16x16x32_f16(af[mi], bf0, acc[mi][0], 0, 0, 0);
      acc[mi][1] = __builtin_amdgcn_mfma_f32_16x16x32_f16(af[mi], bf1, acc[mi][1], 0, 0, 0);
    }
    __builtin_amdgcn_s_setprio(0);
    if (it < 30) {  // phase-2 staging: B-pair for step it+2
      gld16(gB0 + kk, bp + 8192 + loff0);
      gld16(gB1 + kk, bp + 8192 + loff1);
    }
    bf2 = *(const half8*)&Bsb[(wc * 64 + 2 * 16 + fr) * 32 + fc];
    bf3 = *(const half8*)&Bsb[(wc * 64 + 3 * 16 + fr) * 32 + fc];
    __builtin_amdgcn_s_setprio(1);
#pragma unroll
    for (int mi = 0; mi < 8; mi++) {
      acc[mi][2] = __builtin_amdgcn_mfma_f32_16x16x32_f16(af[mi], bf2, acc[mi][2], 0, 0, 0);
      acc[mi][3] = __builtin_amdgcn_mfma_f32_16x16x32_f16(af[mi], bf3, acc[mi][3], 0, 0, 0);
    }
    __builtin_amdgcn_s_setprio(0);
    bufCur = (bufCur == 2) ? 0 : bufCur + 1;
    bufNxt = (bufNxt == 2) ? 0 : bufNxt + 1;
  }

  // epilogue: 4 rounds of 64 rows x 256 cols via LDS (32 KB, overlays ring buffers)
  const int erow = tid >> 3;
  const int rqkr = (erow >> 2) & 3;
#pragma unroll
  for (int r = 0; r < 4; ++r) {
    __syncthreads();
    if (wr == (r >> 1)) {
      const int mib = (r & 1) * 4;
#pragma unroll
      for (int mi2 = 0; mi2 < 4; ++mi2) {
#pragma unroll
        for (int ni = 0; ni < 4; ++ni) {
          int colp = (wc * 64 + ni * 16 + c0f) ^ (rqk << 4);
#pragma unroll
          for (int rr = 0; rr < 4; ++rr) {
            int row_local = mi2 * 16 + rqk * 4 + rr;
            SM[row_local * 256 + colp] = (_Float16)acc[mib + mi2][ni][rr];
          }
        }
      }
    }
    __syncthreads();
    long grow = m0 + r * 64 + erow;
    long dsrow = grow & bcMask;
#pragma unroll
    for (int q = 0; q < 4; ++q) {
      int col = (tid & 7) * 8 + q * 64;
      int colp = col ^ (rqkr << 4);
      half8 vv = *(const half8*)&SM[erow * 256 + colp];
      half8 dv = *(const half8*)&DS[dsrow * (long)K + n0 + col];
      *(half8*)&C[grow * (long)K + n0 + col] = dv * vv;
    }
  }
}

// ---------- output GEMM: C(M x 448, ldc=448) = A*Bt^T (+bias rows < biasRows) ----------
__global__ __launch_bounds__(256, 4)
void gemm_out(const _Float16* __restrict__ A, const _Float16* __restrict__ Bt,
              const _Float16* __restrict__ bias, _Float16* __restrict__ C,
              int Nreal, int ldc, int biasRows, int NR) {
  constexpr int K = 1024;
  __shared__ _Float16 SM[8192];
  _Float16* As = SM;
  _Float16* Bs = SM + 4096;
  _Float16* Ep = SM;
  const int tid = threadIdx.x;
  const int wave = tid >> 6;
  const int lane = tid & 63;
  int rb, cb;
  xcd_decode<4>(blockIdx.x, NR, rb, cb);
  const int n0 = cb * 128;
  const long m0 = (long)rb * 128;

  const int srow0 = (wave * 2 + 0) * 16 + (lane >> 2);
  const int srow1 = (wave * 2 + 1) * 16 + (lane >> 2);
  const int scol = (lane & 3) * 8;
  const _Float16* gA0 = A + (m0 + srow0) * K + scol;
  const _Float16* gA1 = A + (m0 + srow1) * K + scol;
  const _Float16* gB0 = Bt + (long)(n0 + srow0) * K + scol;
  const _Float16* gB1 = Bt + (long)(n0 + srow1) * K + scol;
  _Float16* lA0 = As + (wave * 2 + 0) * 512;
  _Float16* lA1 = As + (wave * 2 + 1) * 512;
  _Float16* lB0 = Bs + (wave * 2 + 0) * 512;
  _Float16* lB1 = Bs + (wave * 2 + 1) * 512;

  const int wm = (wave & 1) * 64;
  const int wn = (wave >> 1) * 64;
  const int fr = lane & 15;
  const int fc = (lane >> 4) * 8;
  const int c0f = lane & 15;
  const int rqk = lane >> 4;
  const int myRound = wave & 1;

  float bv[4];
#pragma unroll
  for (int ni = 0; ni < 4; ni++) bv[ni] = (float)bias[n0 + wn + ni * 16 + c0f];

  const int erow = tid >> 4;
  const int ecol = (tid & 15) * 8;
  const int ecolp = ecol ^ (wave << 4);

  floatx4 acc[4][4];
#pragma unroll
  for (int i = 0; i < 4; i++)
#pragma unroll
    for (int j = 0; j < 4; j++) acc[i][j] = (floatx4)(0.f);

  for (int kk = 0; kk < K; kk += 32) {
    __syncthreads();
    gld16(gA0 + kk, lA0);
    gld16(gA1 + kk, lA1);
    gld16(gB0 + kk, lB0);
    gld16(gB1 + kk, lB1);
    __syncthreads();
    half8 af[4], bf[4];
#pragma unroll
    for (int i = 0; i < 4; i++) af[i] = *(const half8*)&As[(wm + i * 16 + fr) * 32 + fc];
#pragma unroll
    for (int i = 0; i < 4; i++) bf[i] = *(const half8*)&Bs[(wn + i * 16 + fr) * 32 + fc];
#pragma unroll
    for (int mi = 0; mi < 4; mi++)
#pragma unroll
      for (int ni = 0; ni < 4; ni++)
        acc[mi][ni] = __builtin_amdgcn_mfma_f32_16x16x32_f16(af[mi], bf[ni], acc[mi][ni], 0, 0, 0);
  }

#pragma unroll
  for (int r = 0; r < 2; r++) {
    __syncthreads();
    if (myRound == r) {
#pragma unroll
      for (int mi = 0; mi < 4; mi++)
#pragma unroll
        for (int ni = 0; ni < 4; ni++) {
          int colp = (wn + ni * 16 + c0f) ^ (rqk << 4);
#pragma unroll
          for (int rr = 0; rr < 4; rr++) {
            int row_local = mi * 16 + rqk * 4 + rr;
            long grow = m0 + wm + mi * 16 + rqk * 4 + rr;
            float v = acc[mi][ni][rr] + (grow < biasRows ? bv[ni] : 0.f);
            Ep[row_local * 128 + colp] = (_Float16)v;
          }
        }
    }
    __syncthreads();
#pragma unroll
    for (int p = 0; p < 4; p++) {
      int row_local = p * 16 + erow;
      int col = n0 + ecol;
      if (col < Nreal) {
        half8 vv = *(const half8*)&Ep[row_local * 128 + ecolp];
        long row = m0 + r * 64 + row_local;
        *(half8*)&C[row * (long)ldc + col] = vv;
      }
    }
  }
}

// ---------- finalize: softmax mixture + antisymmetric divergence; 1 wave = 1 sample ----------
__global__ __launch_bounds__(256)
void finalize_kernel(const _Float16* __restrict__ O5, void* __restrict__ outp,
                     int chunkBase, int Bc, const int* __restrict__ flag) {
  const int wid = threadIdx.x >> 6;
  const int lane = threadIdx.x & 63;  // lane == mixture index (N_MIX == 64)
  const int lb = blockIdx.x * 4 + wid;
  const long SO = (long)Bc * 448;
  const long base0 = (long)lb * 448;

  union UU { unsigned u; _Float16 h[2]; };

  float lg = (float)O5[base0 + lane];
  float vals[6];
  {
    const unsigned* vp = (const unsigned*)(O5 + base0 + 64 + lane * 6);
#pragma unroll
    for (int q = 0; q < 3; q++) {
      UU c; c.u = vp[q];
      vals[2 * q] = (float)c.h[0];
      vals[2 * q + 1] = (float)c.h[1];
    }
  }
  float dl[4], dv[4][6];
#pragma unroll
  for (int t = 0; t < 4; t++) {
    long bs = (long)(1 + t) * SO + base0;
    dl[t] = (float)O5[bs + lane];
    const unsigned* vp = (const unsigned*)(O5 + bs + 64 + lane * 6);
#pragma unroll
    for (int q = 0; q < 3; q++) {
      UU c; c.u = vp[q];
      dv[t][2 * q] = (float)c.h[0];
      dv[t][2 * q + 1] = (float)c.h[1];
    }
  }
  float mx = lg;
#pragma unroll
  for (int off = 32; off >= 1; off >>= 1) mx = fmaxf(mx, __shfl_xor(mx, off));
  float e = __expf(lg - mx);
  float S = e;
#pragma unroll
  for (int off = 32; off >= 1; off >>= 1) S += __shfl_xor(S, off);
  float pv = e / S;
  float st[4];
#pragma unroll
  for (int t = 0; t < 4; t++) {
    float v = pv * dl[t];
#pragma unroll
    for (int off = 32; off >= 1; off >>= 1) v += __shfl_xor(v, off);
    st[t] = v;
  }
  float da[4][6];
#pragma unroll
  for (int t = 0; t < 4; t++) {
    float w = pv * (dl[t] - st[t]);
#pragma unroll
    for (int k = 0; k < 6; k++) {
      float v = w * vals[k] + pv * dv[t][k];
#pragma unroll
      for (int off = 32; off >= 1; off >>= 1) v += __shfl_xor(v, off);
      da[t][k] = v;
    }
  }
  if (lane == 0) {
    float u0 = da[1][0] + da[2][1] + da[3][2];
    float u1 = -da[0][0] + da[2][3] + da[3][4];
    float u2 = -da[0][1] - da[1][3] + da[3][5];
    float u3 = -da[0][2] - da[1][4] - da[2][5];
    long ob = (long)(chunkBase + lb) * 4;
    if (*flag) {
      float* o = (float*)outp;
      o[ob] = 10.f * u0; o[ob + 1] = u1; o[ob + 2] = u2; o[ob + 3] = u3;
    } else {
      __hip_bfloat16* o = (__hip_bfloat16*)outp;
      o[ob] = __float2bfloat16(10.f * u0);
      o[ob + 1] = __float2bfloat16(u1);
      o[ob + 2] = __float2bfloat16(u2);
      o[ob + 3] = __float2bfloat16(u3);
    }
  }
}

extern "C" void kernel_launch(void* const* d_in, const int* in_sizes, int n_in,
                              void* d_out, int out_size, void* d_ws, size_t ws_size,
                              hipStream_t stream) {
  const void* x = d_in[0];
  const void* W0 = d_in[1];
  const void* b0 = d_in[2];
  const void* Wh = d_in[3];
  const void* bh = d_in[4];
  const void* Wout = d_in[5];
  const void* bout = d_in[6];
  const int B = in_sizes[0] / 4;  // 65536

  // workspace carve (all 256B-aligned)
  char* p = (char*)d_ws;
  int* flag = (int*)p;                 p += 256;
  _Float16* W0c = (_Float16*)p;        p += 4096 * 2;
  _Float16* b0c = (_Float16*)p;        p += 1024 * 2;
  _Float16* bhc = (_Float16*)p;        p += 4096 * 2;
  _Float16* boutc = (_Float16*)p;      p += 512 * 2;
  p += 256 - ((size_t)(p - (char*)d_ws) & 255);
  _Float16* x16 = (_Float16*)p;        p += (size_t)B * 4 * 2;
  _Float16* WhT = (_Float16*)p;        p += (size_t)4 * 1024 * 1024 * 2;
  _Float16* WoutT = (_Float16*)p;      p += (size_t)512 * 1024 * 2;  // padded 448->512 rows
  size_t used = (size_t)(p - (char*)d_ws);
  size_t rem = (ws_size > used) ? (ws_size - used) : 0;
  // per-sample: Ha(10240) + Hb(10240) + DS(2048) + PREo(4480)
  const size_t perS = 10240 + 10240 + 2048 + 4480;
  long bcap = (long)(rem / perS);
  int Bc = 128;
  while ((long)Bc * 2 <= bcap && Bc * 2 <= B) Bc *= 2;  // power of two, divides B
  _Float16* Ha = (_Float16*)p;         p += (size_t)5 * Bc * 1024 * 2;
  _Float16* Hb = (_Float16*)p;         p += (size_t)5 * Bc * 1024 * 2;
  _Float16* DS = (_Float16*)p;         p += (size_t)Bc * 1024 * 2;
  _Float16* PREo = (_Float16*)p;

  // dtype probe + weight prep (once per call)
  probe_kernel<<<1, 256, 0, stream>>>((const unsigned short*)W0, flag);
  cvt_kernel<<<(B * 4 + 255) / 256, 256, 0, stream>>>(x, x16, B * 4, B * 4, flag);
  cvt_kernel<<<16, 256, 0, stream>>>(W0, W0c, 4096, 4096, flag);
  cvt_kernel<<<4, 256, 0, stream>>>(b0, b0c, 1024, 1024, flag);
  cvt_kernel<<<16, 256, 0, stream>>>(bh, bhc, 4096, 4096, flag);
  cvt_kernel<<<2, 256, 0, stream>>>(bout, boutc, 512, 448, flag);
  tr_kernel<<<dim3(32, 32, 4), dim3(32, 8), 0, stream>>>(Wh, WhT, 1024, 1024L * 1024, 1024L * 1024, flag);
  tr_kernel<<<dim3(32, 16, 1), dim3(32, 8), 0, stream>>>(Wout, WoutT, 448, 0L, 0L, flag);

  const int nChunks = B / Bc;
  for (int c = 0; c < nChunks; c++) {
    const int base = c * Bc;
    const int S1 = Bc * 1024;
    _Float16* Hin = Ha;
    _Float16* Hout = Hb;
    layer0_kernel<<<Bc, 256, 0, stream>>>(x16, W0c, b0c, Hin, base, S1);
    const int NR1 = Bc / 128;
    const int NR2row = Bc / 64;   // (4*Bc)/256 row-blocks of the 256^2 tangent GEMM
    const int NRo = 5 * Bc / 128;
    for (int l = 0; l < 4; l++) {
      const _Float16* Wl = WhT + (size_t)l * 1024 * 1024;
      if (Bc >= 256) {
        gemm_h1_256<<<4 * (Bc / 256), 512, 0, stream>>>(
            Hin, Wl, bhc + l * 1024, Hout, DS, Bc / 256);
      } else {
        gemm_h1<<<8 * NR1, 256, 0, stream>>>(
            Hin, Wl, bhc + l * 1024, Hout, DS, NR1);
      }
      gemm_h2<<<4 * NR2row, 512, 0, stream>>>(
          Hin + S1, Wl, Hout + S1, DS, Bc - 1, NR2row);
      _Float16* t = Hin; Hin = Hout; Hout = t;
    }
    gemm_out<<<4 * NRo, 256, 0, stream>>>(
        Hin, WoutT, boutc, PREo, 448, 448, Bc, NRo);
    finalize_kernel<<<Bc / 4, 256, 0, stream>>>(PREo, d_out, base, Bc, flag);
  }
}

// Round 9
// 3934.045 us; speedup vs baseline: 1.0801x; 1.0801x over previous
//
#include <hip/hip_runtime.h>
#include <hip/hip_bf16.h>

typedef _Float16 half8 __attribute__((ext_vector_type(8)));
typedef _Float16 half4 __attribute__((ext_vector_type(4)));
typedef float floatx4 __attribute__((ext_vector_type(4)));

__device__ __forceinline__ float bfu2f(unsigned short u) {
  return __uint_as_float(((unsigned)u) << 16);
}

__device__ __forceinline__ void gld16(const void* g, void* l) {
  __builtin_amdgcn_global_load_lds((const __attribute__((address_space(1))) void*)g,
                                   (__attribute__((address_space(3))) void*)l, 16, 0, 0);
}

__device__ __forceinline__ float fast_sig(float v) {
  return __builtin_amdgcn_rcpf(1.f + __expf(-v));
}

// XCD-aware decode: all NC col-blocks of a row-block share lin%8 -> same XCD.
template <int NC>
__device__ __forceinline__ void xcd_decode(int lin, int NR, int& r, int& c) {
  if (NR & 7) {  // fallback
    c = lin % NC;
    r = lin / NC;
  } else {
    int rl = lin & 7;
    int t = lin >> 3;
    c = t % NC;
    r = (t / NC) * 8 + rl;
  }
}

// ---------- probe: detect fp32 vs bf16 inputs (writes flag: 1 = fp32) ----------
__global__ void probe_kernel(const unsigned short* __restrict__ w0, int* __restrict__ flag) {
  __shared__ int s;
  if (threadIdx.x == 0) s = 0;
  __syncthreads();
  int big = 0;
  for (int i = threadIdx.x; i < 2048; i += 256) {
    unsigned e = (w0[i] >> 7) & 0xFFu;
    if (e >= 134u) big = 1;  // |val| >= 128 impossible for bf16 N(0,0.7) weights
  }
  if (big) atomicOr(&s, 1);
  __syncthreads();
  if (threadIdx.x == 0) *flag = s;
}

// ---------- generic convert to fp16 (zero-pads nIn..nOut) ----------
__global__ void cvt_kernel(const void* __restrict__ in, _Float16* __restrict__ out, int nOut,
                           int nIn, const int* __restrict__ flag) {
  int i = blockIdx.x * 256 + threadIdx.x;
  if (i >= nOut) return;
  float v = 0.f;
  if (i < nIn) v = (*flag) ? ((const float*)in)[i] : bfu2f(((const unsigned short*)in)[i]);
  out[i] = (_Float16)v;
}

// ---------- transpose+convert: out[z][n][k] = in[z][k][n] (n<Nin else 0), K=1024 ----------
__global__ void tr_kernel(const void* __restrict__ in, _Float16* __restrict__ out, int Nin,
                          long inStride, long outStride, const int* __restrict__ flag) {
  __shared__ float tile[32][33];
  const int f = *flag;
  int k0 = blockIdx.x * 32, n0 = blockIdx.y * 32;
  long ib = (long)blockIdx.z * inStride;
  long ob = (long)blockIdx.z * outStride;
  int tx = threadIdx.x, ty = threadIdx.y;  // 32 x 8
#pragma unroll
  for (int i = 0; i < 4; i++) {
    int k = k0 + ty + i * 8, n = n0 + tx;
    float v = 0.f;
    if (n < Nin) {
      long idx = ib + (long)k * Nin + n;
      v = f ? ((const float*)in)[idx] : bfu2f(((const unsigned short*)in)[idx]);
    }
    tile[ty + i * 8][tx] = v;
  }
  __syncthreads();
#pragma unroll
  for (int i = 0; i < 4; i++) {
    int n = n0 + ty + i * 8, k = k0 + tx;
    out[ob + (long)n * 1024 + k] = (_Float16)tile[tx][ty + i * 8];
  }
}

// ---------- layer 0: primal + 4 tangent init ----------
__global__ __launch_bounds__(256)
void layer0_kernel(const _Float16* __restrict__ x16, const _Float16* __restrict__ W0c,
                   const _Float16* __restrict__ b0c, _Float16* __restrict__ H,
                   int chunkBase, int S1) {
  const int lb = blockIdx.x;
  const int t = threadIdx.x;
  const long gb = (long)chunkBase + lb;
  float z0 = (float)x16[gb * 4 + 0];
  float z1 = (float)x16[gb * 4 + 1];
  float z2 = (float)x16[gb * 4 + 2];
  float z3 = (float)x16[gb * 4 + 3];
  const int j0 = t * 4;
  float w[4][4];
#pragma unroll
  for (int i = 0; i < 4; i++) {
    half4 wv = *(const half4*)&W0c[i * 1024 + j0];
#pragma unroll
    for (int jj = 0; jj < 4; jj++) w[i][jj] = (float)wv[jj];
  }
  half4 o[5];
#pragma unroll
  for (int jj = 0; jj < 4; jj++) {
    float pre = z0 * w[0][jj] + z1 * w[1][jj] + z2 * w[2][jj] + z3 * w[3][jj] +
                (float)b0c[j0 + jj];
    float s = fast_sig(pre);
    o[0][jj] = (_Float16)(pre * s);
    float ds = s * (1.f + pre * (1.f - s));
    o[1][jj] = (_Float16)(ds * w[0][jj]);
    o[2][jj] = (_Float16)(ds * w[1][jj]);
    o[3][jj] = (_Float16)(ds * w[2][jj]);
    o[4][jj] = (_Float16)(ds * w[3][jj]);
  }
  long rowbase = (long)lb * 1024 + j0;
#pragma unroll
  for (int s = 0; s < 5; s++) *(half4*)&H[(long)s * S1 + rowbase] = o[s];
}

// ---------- hidden primal GEMM, 128x128 drain-style (unused fallback; kept for TU stability) ----------
__global__ __launch_bounds__(256, 3)
void gemm_h1(const _Float16* __restrict__ A, const _Float16* __restrict__ Bt,
             const _Float16* __restrict__ bias, _Float16* __restrict__ C,
             _Float16* __restrict__ DS, int NR) {
  constexpr int K = 1024;
  __shared__ _Float16 SM[8192];
  _Float16* As = SM;
  _Float16* Bs = SM + 4096;
  _Float16* Ep = SM;
  const int tid = threadIdx.x;
  const int wave = tid >> 6;
  const int lane = tid & 63;
  int rb, cb;
  xcd_decode<8>(blockIdx.x, NR, rb, cb);
  const int n0 = cb * 128;
  const long m0 = (long)rb * 128;

  const int srow0 = (wave * 2 + 0) * 16 + (lane >> 2);
  const int srow1 = (wave * 2 + 1) * 16 + (lane >> 2);
  const int scol = (lane & 3) * 8;
  const _Float16* gA0 = A + (m0 + srow0) * K + scol;
  const _Float16* gA1 = A + (m0 + srow1) * K + scol;
  const _Float16* gB0 = Bt + (long)(n0 + srow0) * K + scol;
  const _Float16* gB1 = Bt + (long)(n0 + srow1) * K + scol;
  _Float16* lA0 = As + (wave * 2 + 0) * 512;
  _Float16* lA1 = As + (wave * 2 + 1) * 512;
  _Float16* lB0 = Bs + (wave * 2 + 0) * 512;
  _Float16* lB1 = Bs + (wave * 2 + 1) * 512;

  const int wm = (wave & 1) * 64;
  const int wn = (wave >> 1) * 64;
  const int fr = lane & 15;
  const int fc = (lane >> 4) * 8;
  const int c0f = lane & 15;
  const int rqk = lane >> 4;
  const int myRound = wave & 1;

  float bv[4];
#pragma unroll
  for (int ni = 0; ni < 4; ni++) bv[ni] = (float)bias[n0 + wn + ni * 16 + c0f];

  const int erow = tid >> 4;
  const int ecol = (tid & 15) * 8;
  const int ecolp = ecol ^ (wave << 4);

  floatx4 acc[4][4];
#pragma unroll
  for (int i = 0; i < 4; i++)
#pragma unroll
    for (int j = 0; j < 4; j++) acc[i][j] = (floatx4)(0.f);

  for (int kk = 0; kk < K; kk += 32) {
    __syncthreads();
    gld16(gA0 + kk, lA0);
    gld16(gA1 + kk, lA1);
    gld16(gB0 + kk, lB0);
    gld16(gB1 + kk, lB1);
    __syncthreads();
    half8 af[4], bf[4];
#pragma unroll
    for (int i = 0; i < 4; i++) af[i] = *(const half8*)&As[(wm + i * 16 + fr) * 32 + fc];
#pragma unroll
    for (int i = 0; i < 4; i++) bf[i] = *(const half8*)&Bs[(wn + i * 16 + fr) * 32 + fc];
#pragma unroll
    for (int mi = 0; mi < 4; mi++)
#pragma unroll
      for (int ni = 0; ni < 4; ni++)
        acc[mi][ni] = __builtin_amdgcn_mfma_f32_16x16x32_f16(af[mi], bf[ni], acc[mi][ni], 0, 0, 0);
  }

#pragma unroll
  for (int r = 0; r < 2; r++) {
    __syncthreads();
    if (myRound == r) {
#pragma unroll
      for (int mi = 0; mi < 4; mi++)
#pragma unroll
        for (int ni = 0; ni < 4; ni++) {
          int colp = (wn + ni * 16 + c0f) ^ (rqk << 4);
#pragma unroll
          for (int rr = 0; rr < 4; rr++) {
            int row_local = mi * 16 + rqk * 4 + rr;
            Ep[row_local * 128 + colp] = (_Float16)(acc[mi][ni][rr] + bv[ni]);
          }
        }
    }
    __syncthreads();
#pragma unroll
    for (int p = 0; p < 4; p++) {
      int row_local = p * 16 + erow;
      half8 vv = *(const half8*)&Ep[row_local * 128 + ecolp];
      long row = m0 + r * 64 + row_local;
      half8 hv, dv;
#pragma unroll
      for (int e = 0; e < 8; e++) {
        float xv = (float)vv[e];
        float sg = fast_sig(xv);
        hv[e] = (_Float16)(xv * sg);
        dv[e] = (_Float16)(sg * (1.f + xv * (1.f - sg)));
      }
      *(half8*)&C[row * (long)K + n0 + ecol] = hv;
      *(half8*)&DS[row * (long)K + n0 + ecol] = dv;
    }
  }
}

// ---------- hidden primal GEMM, 128x256 tile (r6-proven K-loop skeleton) ----------
// v = A*W^T + b; C = silu(v); DS = silu'(v).  M=Bc=8192 -> 64x4 = 256 blocks =
// exactly 1/CU (the r8 256^2 version had only 128 blocks -> half the machine idle).
// Per K-step per wave: 1 A-gld16 (16 rows) + 2 B-gld16 (32 rows) = 3 loads ->
// counted vmcnt(3). Ring-3 x 24KB = 72 KB LDS. Same barrier/stage-split/setprio/
// swizzle-pair as the thrice-verified gemm_h2 loop.
__global__ __launch_bounds__(512, 2)
void gemm_h1_256(const _Float16* __restrict__ A, const _Float16* __restrict__ Bt,
                 const _Float16* __restrict__ bias, _Float16* __restrict__ C,
                 _Float16* __restrict__ DS, int NR) {
  constexpr int K = 1024;
  __shared__ _Float16 SM[36864];  // 3 x (A 4096 + B 8192) elems = 72 KB; epilogue overlays
  const int tid = threadIdx.x;
  const int wave = tid >> 6;
  const int lane = tid & 63;
  int rb, cb;
  xcd_decode<4>(blockIdx.x, NR, rb, cb);
  const long m0 = (long)rb * 128;
  const int n0 = cb * 256;

  const int srowA = wave * 16 + (lane >> 2);   // 8 waves x 16 rows = 128
  const int srowB = wave * 32 + (lane >> 2);   // 8 waves x 32 rows = 256
  const int scol = ((lane & 3) ^ ((lane >> 3) & 3)) * 8;  // pre-swizzled source chunk
  const _Float16* gA0 = A + (m0 + srowA) * K + scol;
  const _Float16* gB0 = Bt + (long)(n0 + srowB) * K + scol;
  const _Float16* gB1 = gB0 + 16 * K;
  const int loffA = wave * 512;
  const int loffB = wave * 1024;

  const int wr = wave >> 2;   // 0..1 -> rows wr*64
  const int wc = wave & 3;    // 0..3 -> cols wc*64
  const int fr = lane & 15;
  const int fc = ((lane >> 4) ^ ((lane >> 1) & 3)) * 8;  // swizzled read slot
  const int rqk = lane >> 4;
  const int c0f = lane & 15;

  float bv[4];
#pragma unroll
  for (int ni = 0; ni < 4; ni++) bv[ni] = (float)bias[n0 + wc * 64 + ni * 16 + c0f];

  floatx4 acc[4][4];
#pragma unroll
  for (int i = 0; i < 4; i++)
#pragma unroll
    for (int j = 0; j < 4; j++) acc[i][j] = (floatx4)(0.f);

  // prologue: stage steps 0 and 1 (FIFO per wave: A, B0, B1 each step)
  {
    _Float16* b0p = SM;
    gld16(gA0 + 0, b0p + loffA);
    gld16(gB0 + 0, b0p + 4096 + loffB);
    gld16(gB1 + 0, b0p + 4096 + loffB + 512);
    _Float16* b1p = SM + 12288;
    gld16(gA0 + 32, b1p + loffA);
    gld16(gB0 + 32, b1p + 4096 + loffB);
    gld16(gB1 + 32, b1p + 4096 + loffB + 512);
  }

  int bufCur = 0;
  int bufNxt = 2;
  for (int it = 0; it < 32; ++it) {
    if (it < 31) __builtin_amdgcn_s_waitcnt(0x0F73);  // vmcnt(3): step it complete
    else         __builtin_amdgcn_s_waitcnt(0x0F70);  // vmcnt(0)
    __builtin_amdgcn_s_barrier();                     // raw: no forced drain of step it+1
    const int kk = (it + 2) * 32;
    _Float16* bp = SM + bufNxt * 12288;
    if (it < 30) {  // phase-1 staging: A for step it+2
      gld16(gA0 + kk, bp + loffA);
    }
    const _Float16* Asb = SM + bufCur * 12288;
    const _Float16* Bsb = Asb + 4096;
    half8 af[4], bf0, bf1, bf2, bf3;
#pragma unroll
    for (int i = 0; i < 4; i++)
      af[i] = *(const half8*)&Asb[(wr * 64 + i * 16 + fr) * 32 + fc];
    bf0 = *(const half8*)&Bsb[(wc * 64 + 0 * 16 + fr) * 32 + fc];
    bf1 = *(const half8*)&Bsb[(wc * 64 + 1 * 16 + fr) * 32 + fc];
    __builtin_amdgcn_s_setprio(1);
#pragma unroll
    for (int mi = 0; mi < 4; mi++) {
      acc[mi][0] = __builtin_amdgcn_mfma_f32_16x16x32_f16(af[mi], bf0, acc[mi][0], 0, 0, 0);
      acc[mi][1] = __builtin_amdgcn_mfma_f32_16x16x32_f16(af[mi], bf1, acc[mi][1], 0, 0, 0);
    }
    __builtin_amdgcn_s_setprio(0);
    if (it < 30) {  // phase-2 staging: B-pair for step it+2
      gld16(gB0 + kk, bp + 4096 + loffB);
      gld16(gB1 + kk, bp + 4096 + loffB + 512);
    }
    bf2 = *(const half8*)&Bsb[(wc * 64 + 2 * 16 + fr) * 32 + fc];
    bf3 = *(const half8*)&Bsb[(wc * 64 + 3 * 16 + fr) * 32 + fc];
    __builtin_amdgcn_s_setprio(1);
#pragma unroll
    for (int mi = 0; mi < 4; mi++) {
      acc[mi][2] = __builtin_amdgcn_mfma_f32_16x16x32_f16(af[mi], bf2, acc[mi][2], 0, 0, 0);
      acc[mi][3] = __builtin_amdgcn_mfma_f32_16x16x32_f16(af[mi], bf3, acc[mi][3], 0, 0, 0);
    }
    __builtin_amdgcn_s_setprio(0);
    bufCur = (bufCur == 2) ? 0 : bufCur + 1;
    bufNxt = (bufNxt == 2) ? 0 : bufNxt + 1;
  }

  // epilogue: 2 rounds of 64 rows x 256 cols via LDS (32 KB, overlays ring buffers);
  // bias added (fp32) at write, silu/silu' computed at read — matches 128^2 h1 numerics.
  const int erow = tid >> 3;
  const int rqkr = (erow >> 2) & 3;
#pragma unroll
  for (int r = 0; r < 2; ++r) {
    __syncthreads();
    if (wr == r) {
#pragma unroll
      for (int mi2 = 0; mi2 < 4; ++mi2) {
#pragma unroll
        for (int ni = 0; ni < 4; ++ni) {
          int colp = (wc * 64 + ni * 16 + c0f) ^ (rqk << 4);
#pragma unroll
          for (int rr = 0; rr < 4; ++rr) {
            int row_local = mi2 * 16 + rqk * 4 + rr;
            SM[row_local * 256 + colp] = (_Float16)(acc[mi2][ni][rr] + bv[ni]);
          }
        }
      }
    }
    __syncthreads();
    long grow = m0 + r * 64 + erow;
#pragma unroll
    for (int q = 0; q < 4; ++q) {
      int col = (tid & 7) * 8 + q * 64;
      int colp = col ^ (rqkr << 4);
      half8 vv = *(const half8*)&SM[erow * 256 + colp];
      half8 hv, dv;
#pragma unroll
      for (int e = 0; e < 8; e++) {
        float xv = (float)vv[e];
        float sg = fast_sig(xv);
        hv[e] = (_Float16)(xv * sg);
        dv[e] = (_Float16)(sg * (1.f + xv * (1.f - sg)));
      }
      *(half8*)&C[grow * (long)K + n0 + col] = hv;
      *(half8*)&DS[grow * (long)K + n0 + col] = dv;
    }
  }
}

// ---------- hidden tangent GEMM, 256x256 tile, 8 waves, single-barrier K-step ----------
// r6-verified form (77 us): ring of 3 LDS buffers, prefetch distance 2, counted
// vmcnt(4) + ONE raw barrier per K-step. r7's BK=64 pairing REGRESSED (88 us) —
// the fine 32-K interleave is the value, not fewer barriers. Do not coarsen.
__global__ __launch_bounds__(512, 2)
void gemm_h2(const _Float16* __restrict__ A, const _Float16* __restrict__ Bt,
             _Float16* __restrict__ C, const _Float16* __restrict__ DS, int bcMask, int NR) {
  constexpr int K = 1024;
  __shared__ _Float16 SM[49152];  // 3 x (A 8192 + B 8192) elems = 96 KB; epilogue overlays
  const int tid = threadIdx.x;
  const int wave = tid >> 6;
  const int lane = tid & 63;
  int rb, cb;
  xcd_decode<4>(blockIdx.x, NR, rb, cb);
  const long m0 = (long)rb * 256;
  const int n0 = cb * 256;

  const int srow = wave * 32 + (lane >> 2);
  const int scol = ((lane & 3) ^ ((lane >> 3) & 3)) * 8;  // pre-swizzled source chunk
  const _Float16* gA0 = A + (m0 + srow) * K + scol;
  const _Float16* gA1 = gA0 + 16 * K;
  const _Float16* gB0 = Bt + (long)(n0 + srow) * K + scol;
  const _Float16* gB1 = gB0 + 16 * K;
  const int loff0 = wave * 1024;
  const int loff1 = loff0 + 512;

  const int wr = wave >> 2;
  const int wc = wave & 3;
  const int fr = lane & 15;
  const int fc = ((lane >> 4) ^ ((lane >> 1) & 3)) * 8;  // swizzled read slot
  const int rqk = lane >> 4;
  const int c0f = lane & 15;

  floatx4 acc[8][4];
#pragma unroll
  for (int i = 0; i < 8; i++)
#pragma unroll
    for (int j = 0; j < 4; j++) acc[i][j] = (floatx4)(0.f);

  {
    _Float16* b0p = SM;
    gld16(gA0 + 0, b0p + loff0);
    gld16(gA1 + 0, b0p + loff1);
    gld16(gB0 + 0, b0p + 8192 + loff0);
    gld16(gB1 + 0, b0p + 8192 + loff1);
    _Float16* b1p = SM + 16384;
    gld16(gA0 + 32, b1p + loff0);
    gld16(gA1 + 32, b1p + loff1);
    gld16(gB0 + 32, b1p + 8192 + loff0);
    gld16(gB1 + 32, b1p + 8192 + loff1);
  }

  int bufCur = 0;
  int bufNxt = 2;
  for (int it = 0; it < 32; ++it) {
    if (it < 31) __builtin_amdgcn_s_waitcnt(0x0F74);  // vmcnt(4): step it complete
    else         __builtin_amdgcn_s_waitcnt(0x0F70);  // vmcnt(0)
    __builtin_amdgcn_s_barrier();                     // raw: no forced drain of step it+1
    const int kk = (it + 2) * 32;
    _Float16* bp = SM + bufNxt * 16384;
    if (it < 30) {  // phase-1 staging: A-pair for step it+2
      gld16(gA0 + kk, bp + loff0);
      gld16(gA1 + kk, bp + loff1);
    }
    const _Float16* Asb = SM + bufCur * 16384;
    const _Float16* Bsb = Asb + 8192;
    half8 af[8], bf0, bf1, bf2, bf3;
#pragma unroll
    for (int i = 0; i < 8; i++)
      af[i] = *(const half8*)&Asb[(wr * 128 + i * 16 + fr) * 32 + fc];
    bf0 = *(const half8*)&Bsb[(wc * 64 + 0 * 16 + fr) * 32 + fc];
    bf1 = *(const half8*)&Bsb[(wc * 64 + 1 * 16 + fr) * 32 + fc];
    __builtin_amdgcn_s_setprio(1);
#pragma unroll
    for (int mi = 0; mi < 8; mi++) {
      acc[mi][0] = __builtin_amdgcn_mfma_f32_16x16x32_f16(af[mi], bf0, acc[mi][0], 0, 0, 0);
      acc[mi][1] = __builtin_amdgcn_mfma_f32_16x16x32_f16(af[mi], bf1, acc[mi][1], 0, 0, 0);
    }
    __builtin_amdgcn_s_setprio(0);
    if (it < 30) {  // phase-2 staging: B-pair for step it+2
      gld16(gB0 + kk, bp + 8192 + loff0);
      gld16(gB1 + kk, bp + 8192 + loff1);
    }
    bf2 = *(const half8*)&Bsb[(wc * 64 + 2 * 16 + fr) * 32 + fc];
    bf3 = *(const half8*)&Bsb[(wc * 64 + 3 * 16 + fr) * 32 + fc];
    __builtin_amdgcn_s_setprio(1);
#pragma unroll
    for (int mi = 0; mi < 8; mi++) {
      acc[mi][2] = __builtin_amdgcn_mfma_f32_16x16x32_f16(af[mi], bf2, acc[mi][2], 0, 0, 0);
      acc[mi][3] = __builtin_amdgcn_mfma_f32_16x16x32_f16(af[mi], bf3, acc[mi][3], 0, 0, 0);
    }
    __builtin_amdgcn_s_setprio(0);
    bufCur = (bufCur == 2) ? 0 : bufCur + 1;
    bufNxt = (bufNxt == 2) ? 0 : bufNxt + 1;
  }

  // epilogue: 4 rounds of 64 rows x 256 cols via LDS (32 KB, overlays ring buffers)
  const int erow = tid >> 3;
  const int rqkr = (erow >> 2) & 3;
#pragma unroll
  for (int r = 0; r < 4; ++r) {
    __syncthreads();
    if (wr == (r >> 1)) {
      const int mib = (r & 1) * 4;
#pragma unroll
      for (int mi2 = 0; mi2 < 4; ++mi2) {
#pragma unroll
        for (int ni = 0; ni < 4; ++ni) {
          int colp = (wc * 64 + ni * 16 + c0f) ^ (rqk << 4);
#pragma unroll
          for (int rr = 0; rr < 4; ++rr) {
            int row_local = mi2 * 16 + rqk * 4 + rr;
            SM[row_local * 256 + colp] = (_Float16)acc[mib + mi2][ni][rr];
          }
        }
      }
    }
    __syncthreads();
    long grow = m0 + r * 64 + erow;
    long dsrow = grow & bcMask;
#pragma unroll
    for (int q = 0; q < 4; ++q) {
      int col = (tid & 7) * 8 + q * 64;
      int colp = col ^ (rqkr << 4);
      half8 vv = *(const half8*)&SM[erow * 256 + colp];
      half8 dv = *(const half8*)&DS[dsrow * (long)K + n0 + col];
      *(half8*)&C[grow * (long)K + n0 + col] = dv * vv;
    }
  }
}

// ---------- output GEMM: C(M x 448, ldc=448) = A*Bt^T (+bias rows < biasRows) ----------
__global__ __launch_bounds__(256, 4)
void gemm_out(const _Float16* __restrict__ A, const _Float16* __restrict__ Bt,
              const _Float16* __restrict__ bias, _Float16* __restrict__ C,
              int Nreal, int ldc, int biasRows, int NR) {
  constexpr int K = 1024;
  __shared__ _Float16 SM[8192];
  _Float16* As = SM;
  _Float16* Bs = SM + 4096;
  _Float16* Ep = SM;
  const int tid = threadIdx.x;
  const int wave = tid >> 6;
  const int lane = tid & 63;
  int rb, cb;
  xcd_decode<4>(blockIdx.x, NR, rb, cb);
  const int n0 = cb * 128;
  const long m0 = (long)rb * 128;

  const int srow0 = (wave * 2 + 0) * 16 + (lane >> 2);
  const int srow1 = (wave * 2 + 1) * 16 + (lane >> 2);
  const int scol = (lane & 3) * 8;
  const _Float16* gA0 = A + (m0 + srow0) * K + scol;
  const _Float16* gA1 = A + (m0 + srow1) * K + scol;
  const _Float16* gB0 = Bt + (long)(n0 + srow0) * K + scol;
  const _Float16* gB1 = Bt + (long)(n0 + srow1) * K + scol;
  _Float16* lA0 = As + (wave * 2 + 0) * 512;
  _Float16* lA1 = As + (wave * 2 + 1) * 512;
  _Float16* lB0 = Bs + (wave * 2 + 0) * 512;
  _Float16* lB1 = Bs + (wave * 2 + 1) * 512;

  const int wm = (wave & 1) * 64;
  const int wn = (wave >> 1) * 64;
  const int fr = lane & 15;
  const int fc = (lane >> 4) * 8;
  const int c0f = lane & 15;
  const int rqk = lane >> 4;
  const int myRound = wave & 1;

  float bv[4];
#pragma unroll
  for (int ni = 0; ni < 4; ni++) bv[ni] = (float)bias[n0 + wn + ni * 16 + c0f];

  const int erow = tid >> 4;
  const int ecol = (tid & 15) * 8;
  const int ecolp = ecol ^ (wave << 4);

  floatx4 acc[4][4];
#pragma unroll
  for (int i = 0; i < 4; i++)
#pragma unroll
    for (int j = 0; j < 4; j++) acc[i][j] = (floatx4)(0.f);

  for (int kk = 0; kk < K; kk += 32) {
    __syncthreads();
    gld16(gA0 + kk, lA0);
    gld16(gA1 + kk, lA1);
    gld16(gB0 + kk, lB0);
    gld16(gB1 + kk, lB1);
    __syncthreads();
    half8 af[4], bf[4];
#pragma unroll
    for (int i = 0; i < 4; i++) af[i] = *(const half8*)&As[(wm + i * 16 + fr) * 32 + fc];
#pragma unroll
    for (int i = 0; i < 4; i++) bf[i] = *(const half8*)&Bs[(wn + i * 16 + fr) * 32 + fc];
#pragma unroll
    for (int mi = 0; mi < 4; mi++)
#pragma unroll
      for (int ni = 0; ni < 4; ni++)
        acc[mi][ni] = __builtin_amdgcn_mfma_f32_16x16x32_f16(af[mi], bf[ni], acc[mi][ni], 0, 0, 0);
  }

#pragma unroll
  for (int r = 0; r < 2; r++) {
    __syncthreads();
    if (myRound == r) {
#pragma unroll
      for (int mi = 0; mi < 4; mi++)
#pragma unroll
        for (int ni = 0; ni < 4; ni++) {
          int colp = (wn + ni * 16 + c0f) ^ (rqk << 4);
#pragma unroll
          for (int rr = 0; rr < 4; rr++) {
            int row_local = mi * 16 + rqk * 4 + rr;
            long grow = m0 + wm + mi * 16 + rqk * 4 + rr;
            float v = acc[mi][ni][rr] + (grow < biasRows ? bv[ni] : 0.f);
            Ep[row_local * 128 + colp] = (_Float16)v;
          }
        }
    }
    __syncthreads();
#pragma unroll
    for (int p = 0; p < 4; p++) {
      int row_local = p * 16 + erow;
      int col = n0 + ecol;
      if (col < Nreal) {
        half8 vv = *(const half8*)&Ep[row_local * 128 + ecolp];
        long row = m0 + r * 64 + row_local;
        *(half8*)&C[row * (long)ldc + col] = vv;
      }
    }
  }
}

// ---------- finalize: softmax mixture + antisymmetric divergence; 1 wave = 1 sample ----------
__global__ __launch_bounds__(256)
void finalize_kernel(const _Float16* __restrict__ O5, void* __restrict__ outp,
                     int chunkBase, int Bc, const int* __restrict__ flag) {
  const int wid = threadIdx.x >> 6;
  const int lane = threadIdx.x & 63;  // lane == mixture index (N_MIX == 64)
  const int lb = blockIdx.x * 4 + wid;
  const long SO = (long)Bc * 448;
  const long base0 = (long)lb * 448;

  union UU { unsigned u; _Float16 h[2]; };

  float lg = (float)O5[base0 + lane];
  float vals[6];
  {
    const unsigned* vp = (const unsigned*)(O5 + base0 + 64 + lane * 6);
#pragma unroll
    for (int q = 0; q < 3; q++) {
      UU c; c.u = vp[q];
      vals[2 * q] = (float)c.h[0];
      vals[2 * q + 1] = (float)c.h[1];
    }
  }
  float dl[4], dv[4][6];
#pragma unroll
  for (int t = 0; t < 4; t++) {
    long bs = (long)(1 + t) * SO + base0;
    dl[t] = (float)O5[bs + lane];
    const unsigned* vp = (const unsigned*)(O5 + bs + 64 + lane * 6);
#pragma unroll
    for (int q = 0; q < 3; q++) {
      UU c; c.u = vp[q];
      dv[t][2 * q] = (float)c.h[0];
      dv[t][2 * q + 1] = (float)c.h[1];
    }
  }
  float mx = lg;
#pragma unroll
  for (int off = 32; off >= 1; off >>= 1) mx = fmaxf(mx, __shfl_xor(mx, off));
  float e = __expf(lg - mx);
  float S = e;
#pragma unroll
  for (int off = 32; off >= 1; off >>= 1) S += __shfl_xor(S, off);
  float pv = e / S;
  float st[4];
#pragma unroll
  for (int t = 0; t < 4; t++) {
    float v = pv * dl[t];
#pragma unroll
    for (int off = 32; off >= 1; off >>= 1) v += __shfl_xor(v, off);
    st[t] = v;
  }
  float da[4][6];
#pragma unroll
  for (int t = 0; t < 4; t++) {
    float w = pv * (dl[t] - st[t]);
#pragma unroll
    for (int k = 0; k < 6; k++) {
      float v = w * vals[k] + pv * dv[t][k];
#pragma unroll
      for (int off = 32; off >= 1; off >>= 1) v += __shfl_xor(v, off);
      da[t][k] = v;
    }
  }
  if (lane == 0) {
    float u0 = da[1][0] + da[2][1] + da[3][2];
    float u1 = -da[0][0] + da[2][3] + da[3][4];
    float u2 = -da[0][1] - da[1][3] + da[3][5];
    float u3 = -da[0][2] - da[1][4] - da[2][5];
    long ob = (long)(chunkBase + lb) * 4;
    if (*flag) {
      float* o = (float*)outp;
      o[ob] = 10.f * u0; o[ob + 1] = u1; o[ob + 2] = u2; o[ob + 3] = u3;
    } else {
      __hip_bfloat16* o = (__hip_bfloat16*)outp;
      o[ob] = __float2bfloat16(10.f * u0);
      o[ob + 1] = __float2bfloat16(u1);
      o[ob + 2] = __float2bfloat16(u2);
      o[ob + 3] = __float2bfloat16(u3);
    }
  }
}

extern "C" void kernel_launch(void* const* d_in, const int* in_sizes, int n_in,
                              void* d_out, int out_size, void* d_ws, size_t ws_size,
                              hipStream_t stream) {
  const void* x = d_in[0];
  const void* W0 = d_in[1];
  const void* b0 = d_in[2];
  const void* Wh = d_in[3];
  const void* bh = d_in[4];
  const void* Wout = d_in[5];
  const void* bout = d_in[6];
  const int B = in_sizes[0] / 4;  // 65536

  // workspace carve (all 256B-aligned)
  char* p = (char*)d_ws;
  int* flag = (int*)p;                 p += 256;
  _Float16* W0c = (_Float16*)p;        p += 4096 * 2;
  _Float16* b0c = (_Float16*)p;        p += 1024 * 2;
  _Float16* bhc = (_Float16*)p;        p += 4096 * 2;
  _Float16* boutc = (_Float16*)p;      p += 512 * 2;
  p += 256 - ((size_t)(p - (char*)d_ws) & 255);
  _Float16* x16 = (_Float16*)p;        p += (size_t)B * 4 * 2;
  _Float16* WhT = (_Float16*)p;        p += (size_t)4 * 1024 * 1024 * 2;
  _Float16* WoutT = (_Float16*)p;      p += (size_t)512 * 1024 * 2;  // padded 448->512 rows
  size_t used = (size_t)(p - (char*)d_ws);
  size_t rem = (ws_size > used) ? (ws_size - used) : 0;
  // per-sample: Ha(10240) + Hb(10240) + DS(2048) + PREo(4480)
  const size_t perS = 10240 + 10240 + 2048 + 4480;
  long bcap = (long)(rem / perS);
  int Bc = 128;
  while ((long)Bc * 2 <= bcap && Bc * 2 <= B) Bc *= 2;  // power of two, divides B
  _Float16* Ha = (_Float16*)p;         p += (size_t)5 * Bc * 1024 * 2;
  _Float16* Hb = (_Float16*)p;         p += (size_t)5 * Bc * 1024 * 2;
  _Float16* DS = (_Float16*)p;         p += (size_t)Bc * 1024 * 2;
  _Float16* PREo = (_Float16*)p;

  // dtype probe + weight prep (once per call)
  probe_kernel<<<1, 256, 0, stream>>>((const unsigned short*)W0, flag);
  cvt_kernel<<<(B * 4 + 255) / 256, 256, 0, stream>>>(x, x16, B * 4, B * 4, flag);
  cvt_kernel<<<16, 256, 0, stream>>>(W0, W0c, 4096, 4096, flag);
  cvt_kernel<<<4, 256, 0, stream>>>(b0, b0c, 1024, 1024, flag);
  cvt_kernel<<<16, 256, 0, stream>>>(bh, bhc, 4096, 4096, flag);
  cvt_kernel<<<2, 256, 0, stream>>>(bout, boutc, 512, 448, flag);
  tr_kernel<<<dim3(32, 32, 4), dim3(32, 8), 0, stream>>>(Wh, WhT, 1024, 1024L * 1024, 1024L * 1024, flag);
  tr_kernel<<<dim3(32, 16, 1), dim3(32, 8), 0, stream>>>(Wout, WoutT, 448, 0L, 0L, flag);

  const int nChunks = B / Bc;
  for (int c = 0; c < nChunks; c++) {
    const int base = c * Bc;
    const int S1 = Bc * 1024;
    _Float16* Hin = Ha;
    _Float16* Hout = Hb;
    layer0_kernel<<<Bc, 256, 0, stream>>>(x16, W0c, b0c, Hin, base, S1);
    const int NR1row = Bc / 128;  // 128-row tiles of the primal GEMM
    const int NR2row = Bc / 64;   // (4*Bc)/256 row-blocks of the 256^2 tangent GEMM
    const int NRo = 5 * Bc / 128;
    for (int l = 0; l < 4; l++) {
      const _Float16* Wl = WhT + (size_t)l * 1024 * 1024;
      gemm_h1_256<<<4 * NR1row, 512, 0, stream>>>(
          Hin, Wl, bhc + l * 1024, Hout, DS, NR1row);
      gemm_h2<<<4 * NR2row, 512, 0, stream>>>(
          Hin + S1, Wl, Hout + S1, DS, Bc - 1, NR2row);
      _Float16* t = Hin; Hin = Hout; Hout = t;
    }
    gemm_out<<<4 * NRo, 256, 0, stream>>>(
        Hin, WoutT, boutc, PREo, 448, 448, Bc, NRo);
    finalize_kernel<<<Bc / 4, 256, 0, stream>>>(PREo, d_out, base, Bc, flag);
  }
}

// Round 10
// 3718.401 us; speedup vs baseline: 1.1428x; 1.0580x over previous
//
#include <hip/hip_runtime.h>
#include <hip/hip_bf16.h>

typedef _Float16 half8 __attribute__((ext_vector_type(8)));
typedef _Float16 half4 __attribute__((ext_vector_type(4)));
typedef float floatx4 __attribute__((ext_vector_type(4)));

__device__ __forceinline__ float bfu2f(unsigned short u) {
  return __uint_as_float(((unsigned)u) << 16);
}

__device__ __forceinline__ void gld16(const void* g, void* l) {
  __builtin_amdgcn_global_load_lds((const __attribute__((address_space(1))) void*)g,
                                   (__attribute__((address_space(3))) void*)l, 16, 0, 0);
}

__device__ __forceinline__ float fast_sig(float v) {
  return __builtin_amdgcn_rcpf(1.f + __expf(-v));
}

// XCD-aware decode: all NC col-blocks of a row-block share lin%8 -> same XCD.
template <int NC>
__device__ __forceinline__ void xcd_decode(int lin, int NR, int& r, int& c) {
  if (NR & 7) {  // fallback
    c = lin % NC;
    r = lin / NC;
  } else {
    int rl = lin & 7;
    int t = lin >> 3;
    c = t % NC;
    r = (t / NC) * 8 + rl;
  }
}

// ---------- probe: detect fp32 vs bf16 inputs (writes flag: 1 = fp32) ----------
__global__ void probe_kernel(const unsigned short* __restrict__ w0, int* __restrict__ flag) {
  __shared__ int s;
  if (threadIdx.x == 0) s = 0;
  __syncthreads();
  int big = 0;
  for (int i = threadIdx.x; i < 2048; i += 256) {
    unsigned e = (w0[i] >> 7) & 0xFFu;
    if (e >= 134u) big = 1;  // |val| >= 128 impossible for bf16 N(0,0.7) weights
  }
  if (big) atomicOr(&s, 1);
  __syncthreads();
  if (threadIdx.x == 0) *flag = s;
}

// ---------- generic convert to fp16 (zero-pads nIn..nOut) ----------
__global__ void cvt_kernel(const void* __restrict__ in, _Float16* __restrict__ out, int nOut,
                           int nIn, const int* __restrict__ flag) {
  int i = blockIdx.x * 256 + threadIdx.x;
  if (i >= nOut) return;
  float v = 0.f;
  if (i < nIn) v = (*flag) ? ((const float*)in)[i] : bfu2f(((const unsigned short*)in)[i]);
  out[i] = (_Float16)v;
}

// ---------- transpose+convert: out[z][n][k] = in[z][k][n] (n<Nin else 0), K=1024 ----------
__global__ void tr_kernel(const void* __restrict__ in, _Float16* __restrict__ out, int Nin,
                          long inStride, long outStride, const int* __restrict__ flag) {
  __shared__ float tile[32][33];
  const int f = *flag;
  int k0 = blockIdx.x * 32, n0 = blockIdx.y * 32;
  long ib = (long)blockIdx.z * inStride;
  long ob = (long)blockIdx.z * outStride;
  int tx = threadIdx.x, ty = threadIdx.y;  // 32 x 8
#pragma unroll
  for (int i = 0; i < 4; i++) {
    int k = k0 + ty + i * 8, n = n0 + tx;
    float v = 0.f;
    if (n < Nin) {
      long idx = ib + (long)k * Nin + n;
      v = f ? ((const float*)in)[idx] : bfu2f(((const unsigned short*)in)[idx]);
    }
    tile[ty + i * 8][tx] = v;
  }
  __syncthreads();
#pragma unroll
  for (int i = 0; i < 4; i++) {
    int n = n0 + ty + i * 8, k = k0 + tx;
    out[ob + (long)n * 1024 + k] = (_Float16)tile[tx][ty + i * 8];
  }
}

// ---------- layer 0: primal + 4 tangent init ----------
__global__ __launch_bounds__(256)
void layer0_kernel(const _Float16* __restrict__ x16, const _Float16* __restrict__ W0c,
                   const _Float16* __restrict__ b0c, _Float16* __restrict__ H,
                   int chunkBase, int S1) {
  const int lb = blockIdx.x;
  const int t = threadIdx.x;
  const long gb = (long)chunkBase + lb;
  float z0 = (float)x16[gb * 4 + 0];
  float z1 = (float)x16[gb * 4 + 1];
  float z2 = (float)x16[gb * 4 + 2];
  float z3 = (float)x16[gb * 4 + 3];
  const int j0 = t * 4;
  float w[4][4];
#pragma unroll
  for (int i = 0; i < 4; i++) {
    half4 wv = *(const half4*)&W0c[i * 1024 + j0];
#pragma unroll
    for (int jj = 0; jj < 4; jj++) w[i][jj] = (float)wv[jj];
  }
  half4 o[5];
#pragma unroll
  for (int jj = 0; jj < 4; jj++) {
    float pre = z0 * w[0][jj] + z1 * w[1][jj] + z2 * w[2][jj] + z3 * w[3][jj] +
                (float)b0c[j0 + jj];
    float s = fast_sig(pre);
    o[0][jj] = (_Float16)(pre * s);
    float ds = s * (1.f + pre * (1.f - s));
    o[1][jj] = (_Float16)(ds * w[0][jj]);
    o[2][jj] = (_Float16)(ds * w[1][jj]);
    o[3][jj] = (_Float16)(ds * w[2][jj]);
    o[4][jj] = (_Float16)(ds * w[3][jj]);
  }
  long rowbase = (long)lb * 1024 + j0;
#pragma unroll
  for (int s = 0; s < 5; s++) *(half4*)&H[(long)s * S1 + rowbase] = o[s];
}

// ---------- hidden primal GEMM, 128x128 drain-style (unused fallback; kept for TU stability) ----------
__global__ __launch_bounds__(256, 3)
void gemm_h1(const _Float16* __restrict__ A, const _Float16* __restrict__ Bt,
             const _Float16* __restrict__ bias, _Float16* __restrict__ C,
             _Float16* __restrict__ DS, int NR) {
  constexpr int K = 1024;
  __shared__ _Float16 SM[8192];
  _Float16* As = SM;
  _Float16* Bs = SM + 4096;
  _Float16* Ep = SM;
  const int tid = threadIdx.x;
  const int wave = tid >> 6;
  const int lane = tid & 63;
  int rb, cb;
  xcd_decode<8>(blockIdx.x, NR, rb, cb);
  const int n0 = cb * 128;
  const long m0 = (long)rb * 128;

  const int srow0 = (wave * 2 + 0) * 16 + (lane >> 2);
  const int srow1 = (wave * 2 + 1) * 16 + (lane >> 2);
  const int scol = (lane & 3) * 8;
  const _Float16* gA0 = A + (m0 + srow0) * K + scol;
  const _Float16* gA1 = A + (m0 + srow1) * K + scol;
  const _Float16* gB0 = Bt + (long)(n0 + srow0) * K + scol;
  const _Float16* gB1 = Bt + (long)(n0 + srow1) * K + scol;
  _Float16* lA0 = As + (wave * 2 + 0) * 512;
  _Float16* lA1 = As + (wave * 2 + 1) * 512;
  _Float16* lB0 = Bs + (wave * 2 + 0) * 512;
  _Float16* lB1 = Bs + (wave * 2 + 1) * 512;

  const int wm = (wave & 1) * 64;
  const int wn = (wave >> 1) * 64;
  const int fr = lane & 15;
  const int fc = (lane >> 4) * 8;
  const int c0f = lane & 15;
  const int rqk = lane >> 4;
  const int myRound = wave & 1;

  float bv[4];
#pragma unroll
  for (int ni = 0; ni < 4; ni++) bv[ni] = (float)bias[n0 + wn + ni * 16 + c0f];

  const int erow = tid >> 4;
  const int ecol = (tid & 15) * 8;
  const int ecolp = ecol ^ (wave << 4);

  floatx4 acc[4][4];
#pragma unroll
  for (int i = 0; i < 4; i++)
#pragma unroll
    for (int j = 0; j < 4; j++) acc[i][j] = (floatx4)(0.f);

  for (int kk = 0; kk < K; kk += 32) {
    __syncthreads();
    gld16(gA0 + kk, lA0);
    gld16(gA1 + kk, lA1);
    gld16(gB0 + kk, lB0);
    gld16(gB1 + kk, lB1);
    __syncthreads();
    half8 af[4], bf[4];
#pragma unroll
    for (int i = 0; i < 4; i++) af[i] = *(const half8*)&As[(wm + i * 16 + fr) * 32 + fc];
#pragma unroll
    for (int i = 0; i < 4; i++) bf[i] = *(const half8*)&Bs[(wn + i * 16 + fr) * 32 + fc];
#pragma unroll
    for (int mi = 0; mi < 4; mi++)
#pragma unroll
      for (int ni = 0; ni < 4; ni++)
        acc[mi][ni] = __builtin_amdgcn_mfma_f32_16x16x32_f16(af[mi], bf[ni], acc[mi][ni], 0, 0, 0);
  }

#pragma unroll
  for (int r = 0; r < 2; r++) {
    __syncthreads();
    if (myRound == r) {
#pragma unroll
      for (int mi = 0; mi < 4; mi++)
#pragma unroll
        for (int ni = 0; ni < 4; ni++) {
          int colp = (wn + ni * 16 + c0f) ^ (rqk << 4);
#pragma unroll
          for (int rr = 0; rr < 4; rr++) {
            int row_local = mi * 16 + rqk * 4 + rr;
            Ep[row_local * 128 + colp] = (_Float16)(acc[mi][ni][rr] + bv[ni]);
          }
        }
    }
    __syncthreads();
#pragma unroll
    for (int p = 0; p < 4; p++) {
      int row_local = p * 16 + erow;
      half8 vv = *(const half8*)&Ep[row_local * 128 + ecolp];
      long row = m0 + r * 64 + row_local;
      half8 hv, dv;
#pragma unroll
      for (int e = 0; e < 8; e++) {
        float xv = (float)vv[e];
        float sg = fast_sig(xv);
        hv[e] = (_Float16)(xv * sg);
        dv[e] = (_Float16)(sg * (1.f + xv * (1.f - sg)));
      }
      *(half8*)&C[row * (long)K + n0 + ecol] = hv;
      *(half8*)&DS[row * (long)K + n0 + ecol] = dv;
    }
  }
}

// ---------- hidden primal GEMM, 128x256 tile (r6-proven K-loop skeleton) ----------
// v = A*W^T + b; C = silu(v); DS = silu'(v).  M=Bc=8192 -> 64x4 = 256 blocks =
// exactly 1/CU. Per K-step per wave: 1 A-gld16 + 2 B-gld16 = 3 loads -> vmcnt(3).
// Ring-3 x 24KB = 72 KB LDS. Verified r9 (3934us total, absmax 0.125).
__global__ __launch_bounds__(512, 2)
void gemm_h1_256(const _Float16* __restrict__ A, const _Float16* __restrict__ Bt,
                 const _Float16* __restrict__ bias, _Float16* __restrict__ C,
                 _Float16* __restrict__ DS, int NR) {
  constexpr int K = 1024;
  __shared__ _Float16 SM[36864];  // 3 x (A 4096 + B 8192) elems = 72 KB; epilogue overlays
  const int tid = threadIdx.x;
  const int wave = tid >> 6;
  const int lane = tid & 63;
  int rb, cb;
  xcd_decode<4>(blockIdx.x, NR, rb, cb);
  const long m0 = (long)rb * 128;
  const int n0 = cb * 256;

  const int srowA = wave * 16 + (lane >> 2);   // 8 waves x 16 rows = 128
  const int srowB = wave * 32 + (lane >> 2);   // 8 waves x 32 rows = 256
  const int scol = ((lane & 3) ^ ((lane >> 3) & 3)) * 8;  // pre-swizzled source chunk
  const _Float16* gA0 = A + (m0 + srowA) * K + scol;
  const _Float16* gB0 = Bt + (long)(n0 + srowB) * K + scol;
  const _Float16* gB1 = gB0 + 16 * K;
  const int loffA = wave * 512;
  const int loffB = wave * 1024;

  const int wr = wave >> 2;   // 0..1 -> rows wr*64
  const int wc = wave & 3;    // 0..3 -> cols wc*64
  const int fr = lane & 15;
  const int fc = ((lane >> 4) ^ ((lane >> 1) & 3)) * 8;  // swizzled read slot
  const int rqk = lane >> 4;
  const int c0f = lane & 15;

  float bv[4];
#pragma unroll
  for (int ni = 0; ni < 4; ni++) bv[ni] = (float)bias[n0 + wc * 64 + ni * 16 + c0f];

  floatx4 acc[4][4];
#pragma unroll
  for (int i = 0; i < 4; i++)
#pragma unroll
    for (int j = 0; j < 4; j++) acc[i][j] = (floatx4)(0.f);

  // prologue: stage steps 0 and 1 (FIFO per wave: A, B0, B1 each step)
  {
    _Float16* b0p = SM;
    gld16(gA0 + 0, b0p + loffA);
    gld16(gB0 + 0, b0p + 4096 + loffB);
    gld16(gB1 + 0, b0p + 4096 + loffB + 512);
    _Float16* b1p = SM + 12288;
    gld16(gA0 + 32, b1p + loffA);
    gld16(gB0 + 32, b1p + 4096 + loffB);
    gld16(gB1 + 32, b1p + 4096 + loffB + 512);
  }

  int bufCur = 0;
  int bufNxt = 2;
  for (int it = 0; it < 32; ++it) {
    if (it < 31) __builtin_amdgcn_s_waitcnt(0x0F73);  // vmcnt(3): step it complete
    else         __builtin_amdgcn_s_waitcnt(0x0F70);  // vmcnt(0)
    __builtin_amdgcn_s_barrier();                     // raw: no forced drain of step it+1
    const int kk = (it + 2) * 32;
    _Float16* bp = SM + bufNxt * 12288;
    if (it < 30) {  // phase-1 staging: A for step it+2
      gld16(gA0 + kk, bp + loffA);
    }
    const _Float16* Asb = SM + bufCur * 12288;
    const _Float16* Bsb = Asb + 4096;
    half8 af[4], bf0, bf1, bf2, bf3;
#pragma unroll
    for (int i = 0; i < 4; i++)
      af[i] = *(const half8*)&Asb[(wr * 64 + i * 16 + fr) * 32 + fc];
    bf0 = *(const half8*)&Bsb[(wc * 64 + 0 * 16 + fr) * 32 + fc];
    bf1 = *(const half8*)&Bsb[(wc * 64 + 1 * 16 + fr) * 32 + fc];
    __builtin_amdgcn_s_setprio(1);
#pragma unroll
    for (int mi = 0; mi < 4; mi++) {
      acc[mi][0] = __builtin_amdgcn_mfma_f32_16x16x32_f16(af[mi], bf0, acc[mi][0], 0, 0, 0);
      acc[mi][1] = __builtin_amdgcn_mfma_f32_16x16x32_f16(af[mi], bf1, acc[mi][1], 0, 0, 0);
    }
    __builtin_amdgcn_s_setprio(0);
    if (it < 30) {  // phase-2 staging: B-pair for step it+2
      gld16(gB0 + kk, bp + 4096 + loffB);
      gld16(gB1 + kk, bp + 4096 + loffB + 512);
    }
    bf2 = *(const half8*)&Bsb[(wc * 64 + 2 * 16 + fr) * 32 + fc];
    bf3 = *(const half8*)&Bsb[(wc * 64 + 3 * 16 + fr) * 32 + fc];
    __builtin_amdgcn_s_setprio(1);
#pragma unroll
    for (int mi = 0; mi < 4; mi++) {
      acc[mi][2] = __builtin_amdgcn_mfma_f32_16x16x32_f16(af[mi], bf2, acc[mi][2], 0, 0, 0);
      acc[mi][3] = __builtin_amdgcn_mfma_f32_16x16x32_f16(af[mi], bf3, acc[mi][3], 0, 0, 0);
    }
    __builtin_amdgcn_s_setprio(0);
    bufCur = (bufCur == 2) ? 0 : bufCur + 1;
    bufNxt = (bufNxt == 2) ? 0 : bufNxt + 1;
  }

  // epilogue: 2 rounds of 64 rows x 256 cols via LDS; bias (fp32) at write,
  // silu/silu' at read — matches 128^2 h1 numerics.
  const int erow = tid >> 3;
  const int rqkr = (erow >> 2) & 3;
#pragma unroll
  for (int r = 0; r < 2; ++r) {
    __syncthreads();
    if (wr == r) {
#pragma unroll
      for (int mi2 = 0; mi2 < 4; ++mi2) {
#pragma unroll
        for (int ni = 0; ni < 4; ++ni) {
          int colp = (wc * 64 + ni * 16 + c0f) ^ (rqk << 4);
#pragma unroll
          for (int rr = 0; rr < 4; ++rr) {
            int row_local = mi2 * 16 + rqk * 4 + rr;
            SM[row_local * 256 + colp] = (_Float16)(acc[mi2][ni][rr] + bv[ni]);
          }
        }
      }
    }
    __syncthreads();
    long grow = m0 + r * 64 + erow;
#pragma unroll
    for (int q = 0; q < 4; ++q) {
      int col = (tid & 7) * 8 + q * 64;
      int colp = col ^ (rqkr << 4);
      half8 vv = *(const half8*)&SM[erow * 256 + colp];
      half8 hv, dv;
#pragma unroll
      for (int e = 0; e < 8; e++) {
        float xv = (float)vv[e];
        float sg = fast_sig(xv);
        hv[e] = (_Float16)(xv * sg);
        dv[e] = (_Float16)(sg * (1.f + xv * (1.f - sg)));
      }
      *(half8*)&C[grow * (long)K + n0 + col] = hv;
      *(half8*)&DS[grow * (long)K + n0 + col] = dv;
    }
  }
}

// ---------- hidden tangent GEMM, 256x256 tile, 8 waves, single-barrier K-step ----------
// r6-verified form (~76 us, reconfirmed r8/r9): ring of 3 LDS buffers, prefetch
// distance 2, counted vmcnt(4) + ONE raw barrier per K-step. r7's BK=64 pairing
// REGRESSED (88 us) — the fine 32-K interleave is the value. Do not coarsen.
__global__ __launch_bounds__(512, 2)
void gemm_h2(const _Float16* __restrict__ A, const _Float16* __restrict__ Bt,
             _Float16* __restrict__ C, const _Float16* __restrict__ DS, int bcMask, int NR) {
  constexpr int K = 1024;
  __shared__ _Float16 SM[49152];  // 3 x (A 8192 + B 8192) elems = 96 KB; epilogue overlays
  const int tid = threadIdx.x;
  const int wave = tid >> 6;
  const int lane = tid & 63;
  int rb, cb;
  xcd_decode<4>(blockIdx.x, NR, rb, cb);
  const long m0 = (long)rb * 256;
  const int n0 = cb * 256;

  const int srow = wave * 32 + (lane >> 2);
  const int scol = ((lane & 3) ^ ((lane >> 3) & 3)) * 8;  // pre-swizzled source chunk
  const _Float16* gA0 = A + (m0 + srow) * K + scol;
  const _Float16* gA1 = gA0 + 16 * K;
  const _Float16* gB0 = Bt + (long)(n0 + srow) * K + scol;
  const _Float16* gB1 = gB0 + 16 * K;
  const int loff0 = wave * 1024;
  const int loff1 = loff0 + 512;

  const int wr = wave >> 2;
  const int wc = wave & 3;
  const int fr = lane & 15;
  const int fc = ((lane >> 4) ^ ((lane >> 1) & 3)) * 8;  // swizzled read slot
  const int rqk = lane >> 4;
  const int c0f = lane & 15;

  floatx4 acc[8][4];
#pragma unroll
  for (int i = 0; i < 8; i++)
#pragma unroll
    for (int j = 0; j < 4; j++) acc[i][j] = (floatx4)(0.f);

  {
    _Float16* b0p = SM;
    gld16(gA0 + 0, b0p + loff0);
    gld16(gA1 + 0, b0p + loff1);
    gld16(gB0 + 0, b0p + 8192 + loff0);
    gld16(gB1 + 0, b0p + 8192 + loff1);
    _Float16* b1p = SM + 16384;
    gld16(gA0 + 32, b1p + loff0);
    gld16(gA1 + 32, b1p + loff1);
    gld16(gB0 + 32, b1p + 8192 + loff0);
    gld16(gB1 + 32, b1p + 8192 + loff1);
  }

  int bufCur = 0;
  int bufNxt = 2;
  for (int it = 0; it < 32; ++it) {
    if (it < 31) __builtin_amdgcn_s_waitcnt(0x0F74);  // vmcnt(4): step it complete
    else         __builtin_amdgcn_s_waitcnt(0x0F70);  // vmcnt(0)
    __builtin_amdgcn_s_barrier();                     // raw: no forced drain of step it+1
    const int kk = (it + 2) * 32;
    _Float16* bp = SM + bufNxt * 16384;
    if (it < 30) {  // phase-1 staging: A-pair for step it+2
      gld16(gA0 + kk, bp + loff0);
      gld16(gA1 + kk, bp + loff1);
    }
    const _Float16* Asb = SM + bufCur * 16384;
    const _Float16* Bsb = Asb + 8192;
    half8 af[8], bf0, bf1, bf2, bf3;
#pragma unroll
    for (int i = 0; i < 8; i++)
      af[i] = *(const half8*)&Asb[(wr * 128 + i * 16 + fr) * 32 + fc];
    bf0 = *(const half8*)&Bsb[(wc * 64 + 0 * 16 + fr) * 32 + fc];
    bf1 = *(const half8*)&Bsb[(wc * 64 + 1 * 16 + fr) * 32 + fc];
    __builtin_amdgcn_s_setprio(1);
#pragma unroll
    for (int mi = 0; mi < 8; mi++) {
      acc[mi][0] = __builtin_amdgcn_mfma_f32_16x16x32_f16(af[mi], bf0, acc[mi][0], 0, 0, 0);
      acc[mi][1] = __builtin_amdgcn_mfma_f32_16x16x32_f16(af[mi], bf1, acc[mi][1], 0, 0, 0);
    }
    __builtin_amdgcn_s_setprio(0);
    if (it < 30) {  // phase-2 staging: B-pair for step it+2
      gld16(gB0 + kk, bp + 8192 + loff0);
      gld16(gB1 + kk, bp + 8192 + loff1);
    }
    bf2 = *(const half8*)&Bsb[(wc * 64 + 2 * 16 + fr) * 32 + fc];
    bf3 = *(const half8*)&Bsb[(wc * 64 + 3 * 16 + fr) * 32 + fc];
    __builtin_amdgcn_s_setprio(1);
#pragma unroll
    for (int mi = 0; mi < 8; mi++) {
      acc[mi][2] = __builtin_amdgcn_mfma_f32_16x16x32_f16(af[mi], bf2, acc[mi][2], 0, 0, 0);
      acc[mi][3] = __builtin_amdgcn_mfma_f32_16x16x32_f16(af[mi], bf3, acc[mi][3], 0, 0, 0);
    }
    __builtin_amdgcn_s_setprio(0);
    bufCur = (bufCur == 2) ? 0 : bufCur + 1;
    bufNxt = (bufNxt == 2) ? 0 : bufNxt + 1;
  }

  // epilogue: 4 rounds of 64 rows x 256 cols via LDS (32 KB, overlays ring buffers)
  const int erow = tid >> 3;
  const int rqkr = (erow >> 2) & 3;
#pragma unroll
  for (int r = 0; r < 4; ++r) {
    __syncthreads();
    if (wr == (r >> 1)) {
      const int mib = (r & 1) * 4;
#pragma unroll
      for (int mi2 = 0; mi2 < 4; ++mi2) {
#pragma unroll
        for (int ni = 0; ni < 4; ++ni) {
          int colp = (wc * 64 + ni * 16 + c0f) ^ (rqk << 4);
#pragma unroll
          for (int rr = 0; rr < 4; ++rr) {
            int row_local = mi2 * 16 + rqk * 4 + rr;
            SM[row_local * 256 + colp] = (_Float16)acc[mib + mi2][ni][rr];
          }
        }
      }
    }
    __syncthreads();
    long grow = m0 + r * 64 + erow;
    long dsrow = grow & bcMask;
#pragma unroll
    for (int q = 0; q < 4; ++q) {
      int col = (tid & 7) * 8 + q * 64;
      int colp = col ^ (rqkr << 4);
      half8 vv = *(const half8*)&SM[erow * 256 + colp];
      half8 dv = *(const half8*)&DS[dsrow * (long)K + n0 + col];
      *(half8*)&C[grow * (long)K + n0 + col] = dv * vv;
    }
  }
}

// ---------- output GEMM, 128x256 tile (r6-proven K-loop skeleton) ----------
// C(M x 448, ldc=448) = A*Bt^T (+bias rows < biasRows). Same pipelined skeleton
// as gemm_h1_256; epilogue: block-uniform bias branch (biasRows % 128 == 0),
// store masked per 64-col block (Nreal % 64 == 0). N padded to 512 -> 2 col-blocks.
__global__ __launch_bounds__(512, 2)
void gemm_out(const _Float16* __restrict__ A, const _Float16* __restrict__ Bt,
              const _Float16* __restrict__ bias, _Float16* __restrict__ C,
              int Nreal, int ldc, int biasRows, int NR) {
  constexpr int K = 1024;
  __shared__ _Float16 SM[36864];  // 3 x (A 4096 + B 8192) elems = 72 KB
  const int tid = threadIdx.x;
  const int wave = tid >> 6;
  const int lane = tid & 63;
  int rb, cb;
  xcd_decode<2>(blockIdx.x, NR, rb, cb);
  const long m0 = (long)rb * 128;
  const int n0 = cb * 256;

  const int srowA = wave * 16 + (lane >> 2);
  const int srowB = wave * 32 + (lane >> 2);
  const int scol = ((lane & 3) ^ ((lane >> 3) & 3)) * 8;
  const _Float16* gA0 = A + (m0 + srowA) * K + scol;
  const _Float16* gB0 = Bt + (long)(n0 + srowB) * K + scol;
  const _Float16* gB1 = gB0 + 16 * K;
  const int loffA = wave * 512;
  const int loffB = wave * 1024;

  const int wr = wave >> 2;
  const int wc = wave & 3;
  const int fr = lane & 15;
  const int fc = ((lane >> 4) ^ ((lane >> 1) & 3)) * 8;
  const int rqk = lane >> 4;
  const int c0f = lane & 15;

  float bv[4];
#pragma unroll
  for (int ni = 0; ni < 4; ni++) bv[ni] = (float)bias[n0 + wc * 64 + ni * 16 + c0f];

  floatx4 acc[4][4];
#pragma unroll
  for (int i = 0; i < 4; i++)
#pragma unroll
    for (int j = 0; j < 4; j++) acc[i][j] = (floatx4)(0.f);

  {
    _Float16* b0p = SM;
    gld16(gA0 + 0, b0p + loffA);
    gld16(gB0 + 0, b0p + 4096 + loffB);
    gld16(gB1 + 0, b0p + 4096 + loffB + 512);
    _Float16* b1p = SM + 12288;
    gld16(gA0 + 32, b1p + loffA);
    gld16(gB0 + 32, b1p + 4096 + loffB);
    gld16(gB1 + 32, b1p + 4096 + loffB + 512);
  }

  int bufCur = 0;
  int bufNxt = 2;
  for (int it = 0; it < 32; ++it) {
    if (it < 31) __builtin_amdgcn_s_waitcnt(0x0F73);  // vmcnt(3)
    else         __builtin_amdgcn_s_waitcnt(0x0F70);  // vmcnt(0)
    __builtin_amdgcn_s_barrier();
    const int kk = (it + 2) * 32;
    _Float16* bp = SM + bufNxt * 12288;
    if (it < 30) {
      gld16(gA0 + kk, bp + loffA);
    }
    const _Float16* Asb = SM + bufCur * 12288;
    const _Float16* Bsb = Asb + 4096;
    half8 af[4], bf0, bf1, bf2, bf3;
#pragma unroll
    for (int i = 0; i < 4; i++)
      af[i] = *(const half8*)&Asb[(wr * 64 + i * 16 + fr) * 32 + fc];
    bf0 = *(const half8*)&Bsb[(wc * 64 + 0 * 16 + fr) * 32 + fc];
    bf1 = *(const half8*)&Bsb[(wc * 64 + 1 * 16 + fr) * 32 + fc];
    __builtin_amdgcn_s_setprio(1);
#pragma unroll
    for (int mi = 0; mi < 4; mi++) {
      acc[mi][0] = __builtin_amdgcn_mfma_f32_16x16x32_f16(af[mi], bf0, acc[mi][0], 0, 0, 0);
      acc[mi][1] = __builtin_amdgcn_mfma_f32_16x16x32_f16(af[mi], bf1, acc[mi][1], 0, 0, 0);
    }
    __builtin_amdgcn_s_setprio(0);
    if (it < 30) {
      gld16(gB0 + kk, bp + 4096 + loffB);
      gld16(gB1 + kk, bp + 4096 + loffB + 512);
    }
    bf2 = *(const half8*)&Bsb[(wc * 64 + 2 * 16 + fr) * 32 + fc];
    bf3 = *(const half8*)&Bsb[(wc * 64 + 3 * 16 + fr) * 32 + fc];
    __builtin_amdgcn_s_setprio(1);
#pragma unroll
    for (int mi = 0; mi < 4; mi++) {
      acc[mi][2] = __builtin_amdgcn_mfma_f32_16x16x32_f16(af[mi], bf2, acc[mi][2], 0, 0, 0);
      acc[mi][3] = __builtin_amdgcn_mfma_f32_16x16x32_f16(af[mi], bf3, acc[mi][3], 0, 0, 0);
    }
    __builtin_amdgcn_s_setprio(0);
    bufCur = (bufCur == 2) ? 0 : bufCur + 1;
    bufNxt = (bufNxt == 2) ? 0 : bufNxt + 1;
  }

  // epilogue: 2 rounds of 64 rows x 256 cols via LDS; bias at write (fp32,
  // per-row condition — block-uniform since biasRows % 128 == 0); masked store.
  const int erow = tid >> 3;
  const int rqkr = (erow >> 2) & 3;
#pragma unroll
  for (int r = 0; r < 2; ++r) {
    __syncthreads();
    if (wr == r) {
#pragma unroll
      for (int mi2 = 0; mi2 < 4; ++mi2) {
#pragma unroll
        for (int ni = 0; ni < 4; ++ni) {
          int colp = (wc * 64 + ni * 16 + c0f) ^ (rqk << 4);
#pragma unroll
          for (int rr = 0; rr < 4; ++rr) {
            int row_local = mi2 * 16 + rqk * 4 + rr;
            long grow = m0 + r * 64 + row_local;
            float v = acc[mi2][ni][rr] + (grow < biasRows ? bv[ni] : 0.f);
            SM[row_local * 256 + colp] = (_Float16)v;
          }
        }
      }
    }
    __syncthreads();
    long grow = m0 + r * 64 + erow;
#pragma unroll
    for (int q = 0; q < 4; ++q) {
      int col = (tid & 7) * 8 + q * 64;
      if (n0 + q * 64 < Nreal) {
        int colp = col ^ (rqkr << 4);
        half8 vv = *(const half8*)&SM[erow * 256 + colp];
        *(half8*)&C[grow * (long)ldc + n0 + col] = vv;
      }
    }
  }
}

// ---------- finalize: softmax mixture + antisymmetric divergence; 1 wave = 1 sample ----------
__global__ __launch_bounds__(256)
void finalize_kernel(const _Float16* __restrict__ O5, void* __restrict__ outp,
                     int chunkBase, int Bc, const int* __restrict__ flag) {
  const int wid = threadIdx.x >> 6;
  const int lane = threadIdx.x & 63;  // lane == mixture index (N_MIX == 64)
  const int lb = blockIdx.x * 4 + wid;
  const long SO = (long)Bc * 448;
  const long base0 = (long)lb * 448;

  union UU { unsigned u; _Float16 h[2]; };

  float lg = (float)O5[base0 + lane];
  float vals[6];
  {
    const unsigned* vp = (const unsigned*)(O5 + base0 + 64 + lane * 6);
#pragma unroll
    for (int q = 0; q < 3; q++) {
      UU c; c.u = vp[q];
      vals[2 * q] = (float)c.h[0];
      vals[2 * q + 1] = (float)c.h[1];
    }
  }
  float dl[4], dv[4][6];
#pragma unroll
  for (int t = 0; t < 4; t++) {
    long bs = (long)(1 + t) * SO + base0;
    dl[t] = (float)O5[bs + lane];
    const unsigned* vp = (const unsigned*)(O5 + bs + 64 + lane * 6);
#pragma unroll
    for (int q = 0; q < 3; q++) {
      UU c; c.u = vp[q];
      dv[t][2 * q] = (float)c.h[0];
      dv[t][2 * q + 1] = (float)c.h[1];
    }
  }
  float mx = lg;
#pragma unroll
  for (int off = 32; off >= 1; off >>= 1) mx = fmaxf(mx, __shfl_xor(mx, off));
  float e = __expf(lg - mx);
  float S = e;
#pragma unroll
  for (int off = 32; off >= 1; off >>= 1) S += __shfl_xor(S, off);
  float pv = e / S;
  float st[4];
#pragma unroll
  for (int t = 0; t < 4; t++) {
    float v = pv * dl[t];
#pragma unroll
    for (int off = 32; off >= 1; off >>= 1) v += __shfl_xor(v, off);
    st[t] = v;
  }
  float da[4][6];
#pragma unroll
  for (int t = 0; t < 4; t++) {
    float w = pv * (dl[t] - st[t]);
#pragma unroll
    for (int k = 0; k < 6; k++) {
      float v = w * vals[k] + pv * dv[t][k];
#pragma unroll
      for (int off = 32; off >= 1; off >>= 1) v += __shfl_xor(v, off);
      da[t][k] = v;
    }
  }
  if (lane == 0) {
    float u0 = da[1][0] + da[2][1] + da[3][2];
    float u1 = -da[0][0] + da[2][3] + da[3][4];
    float u2 = -da[0][1] - da[1][3] + da[3][5];
    float u3 = -da[0][2] - da[1][4] - da[2][5];
    long ob = (long)(chunkBase + lb) * 4;
    if (*flag) {
      float* o = (float*)outp;
      o[ob] = 10.f * u0; o[ob + 1] = u1; o[ob + 2] = u2; o[ob + 3] = u3;
    } else {
      __hip_bfloat16* o = (__hip_bfloat16*)outp;
      o[ob] = __float2bfloat16(10.f * u0);
      o[ob + 1] = __float2bfloat16(u1);
      o[ob + 2] = __float2bfloat16(u2);
      o[ob + 3] = __float2bfloat16(u3);
    }
  }
}

extern "C" void kernel_launch(void* const* d_in, const int* in_sizes, int n_in,
                              void* d_out, int out_size, void* d_ws, size_t ws_size,
                              hipStream_t stream) {
  const void* x = d_in[0];
  const void* W0 = d_in[1];
  const void* b0 = d_in[2];
  const void* Wh = d_in[3];
  const void* bh = d_in[4];
  const void* Wout = d_in[5];
  const void* bout = d_in[6];
  const int B = in_sizes[0] / 4;  // 65536

  // workspace carve (all 256B-aligned)
  char* p = (char*)d_ws;
  int* flag = (int*)p;                 p += 256;
  _Float16* W0c = (_Float16*)p;        p += 4096 * 2;
  _Float16* b0c = (_Float16*)p;        p += 1024 * 2;
  _Float16* bhc = (_Float16*)p;        p += 4096 * 2;
  _Float16* boutc = (_Float16*)p;      p += 512 * 2;
  p += 256 - ((size_t)(p - (char*)d_ws) & 255);
  _Float16* x16 = (_Float16*)p;        p += (size_t)B * 4 * 2;
  _Float16* WhT = (_Float16*)p;        p += (size_t)4 * 1024 * 1024 * 2;
  _Float16* WoutT = (_Float16*)p;      p += (size_t)512 * 1024 * 2;  // padded 448->512 rows
  size_t used = (size_t)(p - (char*)d_ws);
  size_t rem = (ws_size > used) ? (ws_size - used) : 0;
  // per-sample: Ha(10240) + Hb(10240) + DS(2048) + PREo(4480)
  const size_t perS = 10240 + 10240 + 2048 + 4480;
  long bcap = (long)(rem / perS);
  int Bc = 128;
  while ((long)Bc * 2 <= bcap && Bc * 2 <= B) Bc *= 2;  // power of two, divides B
  _Float16* Ha = (_Float16*)p;         p += (size_t)5 * Bc * 1024 * 2;
  _Float16* Hb = (_Float16*)p;         p += (size_t)5 * Bc * 1024 * 2;
  _Float16* DS = (_Float16*)p;         p += (size_t)Bc * 1024 * 2;
  _Float16* PREo = (_Float16*)p;

  // dtype probe + weight prep (once per call)
  probe_kernel<<<1, 256, 0, stream>>>((const unsigned short*)W0, flag);
  cvt_kernel<<<(B * 4 + 255) / 256, 256, 0, stream>>>(x, x16, B * 4, B * 4, flag);
  cvt_kernel<<<16, 256, 0, stream>>>(W0, W0c, 4096, 4096, flag);
  cvt_kernel<<<4, 256, 0, stream>>>(b0, b0c, 1024, 1024, flag);
  cvt_kernel<<<16, 256, 0, stream>>>(bh, bhc, 4096, 4096, flag);
  cvt_kernel<<<2, 256, 0, stream>>>(bout, boutc, 512, 448, flag);
  tr_kernel<<<dim3(32, 32, 4), dim3(32, 8), 0, stream>>>(Wh, WhT, 1024, 1024L * 1024, 1024L * 1024, flag);
  tr_kernel<<<dim3(32, 16, 1), dim3(32, 8), 0, stream>>>(Wout, WoutT, 448, 0L, 0L, flag);

  const int nChunks = B / Bc;
  for (int c = 0; c < nChunks; c++) {
    const int base = c * Bc;
    const int S1 = Bc * 1024;
    _Float16* Hin = Ha;
    _Float16* Hout = Hb;
    layer0_kernel<<<Bc, 256, 0, stream>>>(x16, W0c, b0c, Hin, base, S1);
    const int NR1row = Bc / 128;      // 128-row tiles of the primal GEMM
    const int NR2row = Bc / 64;       // row-blocks of the 256^2 tangent GEMM
    const int NRoRow = 5 * Bc / 128;  // 128-row tiles of the output GEMM
    for (int l = 0; l < 4; l++) {
      const _Float16* Wl = WhT + (size_t)l * 1024 * 1024;
      gemm_h1_256<<<4 * NR1row, 512, 0, stream>>>(
          Hin, Wl, bhc + l * 1024, Hout, DS, NR1row);
      gemm_h2<<<4 * NR2row, 512, 0, stream>>>(
          Hin + S1, Wl, Hout + S1, DS, Bc - 1, NR2row);
      _Float16* t = Hin; Hin = Hout; Hout = t;
    }
    gemm_out<<<2 * NRoRow, 512, 0, stream>>>(
        Hin, WoutT, boutc, PREo, 448, 448, Bc, NRoRow);
    finalize_kernel<<<Bc / 4, 256, 0, stream>>>(PREo, d_out, base, Bc, flag);
  }
}